// Round 10
// baseline (463.921 us; speedup 1.0000x reference)
//
#include <hip/hip_runtime.h>
#include <hip/hip_bf16.h>

// Problem constants
#define BB 4
#define TT 1024
#define DD 1024
#define HH 16
#define KK 64
#define VV 64
#define WIN 256
#define MARKER_ID 50251
#define PSA 5120   // bf16 all-proj row stride: K|V|Q|KL|VL
#define PSB 3072   // epilogue-cat row stride (gdn|local|retr)
#define NPROJ 5248 // proj GEMM N: 5120 bf16 + 128 gates(48+80 pad)

typedef short bfrag8 __attribute__((ext_vector_type(8)));
typedef float f32x4 __attribute__((ext_vector_type(4)));

static __device__ __forceinline__ unsigned short f2bf(float f) {
  __hip_bfloat16 h = __float2bfloat16(f);
  union { __hip_bfloat16 h; unsigned short u; } cv;
  cv.h = h;
  return cv.u;
}
static __device__ __forceinline__ float bf2f(unsigned short u) {
  union { unsigned int i; float f; } c;
  c.i = ((unsigned int)u) << 16;
  return c.f;
}
// Async global->LDS, 16B per lane. LDS dest = wave-uniform base + lane*16.
static __device__ __forceinline__ void gld_lds16(const unsigned short* g,
                                                 unsigned short* l) {
  __builtin_amdgcn_global_load_lds(
      (const __attribute__((address_space(1))) void*)g,
      (__attribute__((address_space(3))) void*)l, 16, 0, 0);
}

// ---------------------------------------------------------------------------
// RMSNorm body: xnb (bf16) = x / sqrt(mean(x^2)+eps) * norm_w. One block/row.
// ---------------------------------------------------------------------------
static __device__ __forceinline__ void rmsnorm_body(
    int row, const float* __restrict__ x, const float* __restrict__ nw,
    unsigned short* __restrict__ xnb, float* red) {
  int tid = threadIdx.x;
  const float4* xr = (const float4*)(x + (size_t)row * DD);
  float4 v = xr[tid];
  float ss = v.x * v.x + v.y * v.y + v.z * v.z + v.w * v.w;
#pragma unroll
  for (int off = 32; off; off >>= 1) ss += __shfl_xor(ss, off);
  int wid = tid >> 6;
  if ((tid & 63) == 0) red[wid] = ss;
  __syncthreads();
  float tot = red[0] + red[1] + red[2] + red[3];
  float inv = 1.0f / sqrtf(tot * (1.0f / DD) + 1e-6f);
  const float4* wr = (const float4*)nw;
  float4 wv = wr[tid];
  ushort4 o;
  o.x = f2bf(v.x * inv * wv.x);
  o.y = f2bf(v.y * inv * wv.y);
  o.z = f2bf(v.z * inv * wv.z);
  o.w = f2bf(v.w * inv * wv.w);
  *(ushort4*)&xnb[(size_t)row * DD + tid * 4] = o;
}

// ---------------------------------------------------------------------------
// Convert weights body: fp32 [K][N] -> bf16 [N][K] concatenated buffers.
// z=0..7: 1024x1024 weights. z=8: gate weights + zero-pad.
// ---------------------------------------------------------------------------
static __device__ __forceinline__ void convert_body(
    int xb, int yb, int zb, const float* W0, const float* W1, const float* W2,
    const float* W3, const float* W4, const float* W5, const float* W6,
    const float* W7, const float* Wb, const float* Wg, const float* Wgt,
    unsigned short* C5, unsigned short* C3, float (*Ts)[68]) {
  int tid = threadIdx.x;
  if (zb == 8) {
    if (xb != 0) return;
    int k0 = yb * 64;
    for (int e = tid; e < 3 * 16 * 64; e += 256) {
      int w = e >> 10;
      int h = (e >> 6) & 15;
      int kk = e & 63;
      const float* Ws = (w == 0) ? Wb : (w == 1) ? Wg : Wgt;
      C5[(size_t)(5120 + w * 16 + h) * 1024 + k0 + kk] =
          f2bf(Ws[(size_t)(k0 + kk) * 16 + h]);
    }
    for (int e = tid; e < 80 * 64; e += 256) {
      int r = e >> 6, kk = e & 63;
      C5[(size_t)(5168 + r) * 1024 + k0 + kk] = 0;
    }
    return;
  }
  const float* W;
  unsigned short* T;
  int stride;
  float scale = 1.f;
  switch (zb) {
    case 0: W = W0; T = C5 + 0 * 1024 * 1024; stride = 1024; break;
    case 1: W = W1; T = C5 + 1 * 1024 * 1024; stride = 1024; break;
    case 2: W = W2; T = C5 + 2 * 1024 * 1024; stride = 1024; break;
    case 3: W = W3; T = C5 + 3 * 1024 * 1024; stride = 1024; break;
    case 4: W = W4; T = C5 + 4 * 1024 * 1024; stride = 1024; break;
    case 5: W = W5; T = C3 + 0; stride = PSB; break;
    case 6: W = W6; T = C3 + 1024; stride = PSB; scale = 0.3f; break;
    default: W = W7; T = C3 + 2048; stride = PSB; break;
  }
  int n0 = xb * 64, k0 = yb * 64;
#pragma unroll
  for (int p = 0; p < 4; ++p) {
    int e = p * 256 + tid;
    int k = e >> 4, nq = e & 15;
    float4 w = *(const float4*)&W[(size_t)(k0 + k) * 1024 + n0 + nq * 4];
    Ts[nq * 4 + 0][k] = w.x;
    Ts[nq * 4 + 1][k] = w.y;
    Ts[nq * 4 + 2][k] = w.z;
    Ts[nq * 4 + 3][k] = w.w;
  }
  __syncthreads();
#pragma unroll
  for (int p = 0; p < 4; ++p) {
    int e = p * 256 + tid;
    int n = e >> 4, kq = e & 15;
    float4 v = *(const float4*)&Ts[n][kq * 4];
    ushort4 u;
    u.x = f2bf(v.x * scale);
    u.y = f2bf(v.y * scale);
    u.z = f2bf(v.z * scale);
    u.w = f2bf(v.w * scale);
    *(ushort4*)&T[(size_t)(n0 + n) * stride + k0 + kq * 4] = u;
  }
}

// ---------------------------------------------------------------------------
// Fused prep: blocks 0..4095 rmsnorm; 4096..6399 convert_wt (decode x,y,z).
// ---------------------------------------------------------------------------
__global__ __launch_bounds__(256) void prep_kernel(
    const float* __restrict__ x, const float* __restrict__ nw,
    unsigned short* __restrict__ xnb, const float* W0, const float* W1,
    const float* W2, const float* W3, const float* W4, const float* W5,
    const float* W6, const float* W7, const float* Wb, const float* Wg,
    const float* Wgt, unsigned short* C5, unsigned short* C3) {
  __shared__ __align__(16) float Ts[64][68];
  int f = blockIdx.x;
  if (f < 4096) {
    rmsnorm_body(f, x, nw, xnb, &Ts[0][0]);
  } else {
    int c = f - 4096;  // 0..2303 = 9 z * 16 y * 16 x
    convert_body(c & 15, (c >> 4) & 15, c >> 8, W0, W1, W2, W3, W4, W5, W6, W7,
                 Wb, Wg, Wgt, C5, C3, Ts);
  }
}

// ---------------------------------------------------------------------------
// Epilogue GEMM: out = x + ACAT[4096][3072] @ WTcat3[1024][3072]^T.
// 128M x 64N tile -> 512 blocks (2/CU). XCD swizzle. Grid MUST be (16, 32).
// Counted-vmcnt 2-deep pipeline (measured winner for this kernel, R2).
// ---------------------------------------------------------------------------
__global__ __launch_bounds__(256) void gemm_out_kernel(
    const unsigned short* __restrict__ A, const unsigned short* __restrict__ BT,
    float* __restrict__ C, const float* __restrict__ addp, int M, int N,
    int K) {
  __shared__ unsigned short As[2][128][32];
  __shared__ unsigned short Bs[2][64][32];
  int flat = blockIdx.y * gridDim.x + blockIdx.x;
  int xcd = flat & 7, local = flat >> 3;
  int m0 = (xcd * 4 + (local & 3)) * 128;
  int n0 = (local >> 2) * 64;
  int tid = threadIdx.x;
  int wave = tid >> 6, lane = tid & 63;
  int wm = wave * 32;
  int r16 = lane & 15, quad = lane >> 4;
  int lrow = lane >> 2, lcol = (lane & 3) * 8;

  f32x4 acc[2][4];
#pragma unroll
  for (int i = 0; i < 2; ++i)
#pragma unroll
    for (int j = 0; j < 4; ++j) acc[i][j] = {0.f, 0.f, 0.f, 0.f};

  auto STAGE = [&](int buf, int kt) {
#pragma unroll
    for (int q = 0; q < 2; ++q) {
      int rb = (wave * 2 + q) * 16;
      gld_lds16(&A[(size_t)(m0 + rb + lrow) * K + kt + lcol], &As[buf][rb][0]);
    }
    {
      int rb = wave * 16;
      gld_lds16(&BT[(size_t)(n0 + rb + lrow) * K + kt + lcol], &Bs[buf][rb][0]);
    }
  };
  auto COMPUTE = [&](int buf) {
    bfrag8 af[2], bq[4];
#pragma unroll
    for (int i = 0; i < 2; ++i)
      af[i] = *(const bfrag8*)&As[buf][wm + i * 16 + r16][quad * 8];
#pragma unroll
    for (int j = 0; j < 4; ++j)
      bq[j] = *(const bfrag8*)&Bs[buf][j * 16 + r16][quad * 8];
#pragma unroll
    for (int i = 0; i < 2; ++i)
#pragma unroll
      for (int j = 0; j < 4; ++j)
        acc[i][j] = __builtin_amdgcn_mfma_f32_16x16x32_bf16(af[i], bq[j],
                                                            acc[i][j], 0, 0, 0);
  };

  // prologue: 2 tiles in flight (3 loads/wave each)
  STAGE(0, 0);
  STAGE(1, 32);
  asm volatile("s_waitcnt vmcnt(3)" ::: "memory");  // tile 0 landed
  __builtin_amdgcn_s_barrier();
  __builtin_amdgcn_sched_barrier(0);

  int cur = 0;
  for (int kt = 64; kt < K; kt += 32) {
    COMPUTE(cur);
    __builtin_amdgcn_s_barrier();       // all waves done reading buf[cur]
    STAGE(cur, kt);                     // refill buf[cur] with tile kt
    asm volatile("s_waitcnt vmcnt(3)" ::: "memory");  // tile in buf[cur^1] landed
    __builtin_amdgcn_s_barrier();
    __builtin_amdgcn_sched_barrier(0);  // keep next ds_reads below the barrier
    cur ^= 1;
  }
  COMPUTE(cur);
  asm volatile("s_waitcnt vmcnt(0)" ::: "memory");
  __builtin_amdgcn_s_barrier();
  __builtin_amdgcn_sched_barrier(0);
  COMPUTE(cur ^ 1);

#pragma unroll
  for (int i = 0; i < 2; ++i) {
#pragma unroll
    for (int r = 0; r < 4; ++r) {
      int row = m0 + wm + i * 16 + quad * 4 + r;
#pragma unroll
      for (int j = 0; j < 4; ++j) {
        int col = n0 + j * 16 + r16;
        size_t idx = (size_t)row * N + col;
        C[idx] = addp[idx] + acc[i][j][r];
      }
    }
  }
}

// ---------------------------------------------------------------------------
// Fused projection GEMM (R5 measured winner: 68us). Grid MUST be (41,32).
// ---------------------------------------------------------------------------
__global__ __launch_bounds__(256, 4) void gemm_proj_kernel(
    const unsigned short* __restrict__ A, const unsigned short* __restrict__ BT,
    unsigned short* __restrict__ PALL, float* __restrict__ SPRJ) {
  const int K = 1024;
  __shared__ unsigned short As[2][128][32];
  __shared__ unsigned short Bs[2][128][32];
  int flat = blockIdx.y * gridDim.x + blockIdx.x;  // 0..1311
  int xcd = flat & 7, local = flat >> 3;           // local 0..163
  int mi = local & 3, ni = local >> 2;             // mi fast (L2 B-reuse)
  int m0 = (xcd * 4 + mi) * 128;
  int n0 = ni * 128;
  int tid = threadIdx.x;
  int wave = tid >> 6, lane = tid & 63;
  int wm = (wave & 1) * 64, wn = (wave >> 1) * 64;
  int r16 = lane & 15, quad = lane >> 4;
  int lrow = lane >> 2, lcol = (lane & 3) * 8;

  f32x4 acc[4][4];
#pragma unroll
  for (int i = 0; i < 4; ++i)
#pragma unroll
    for (int j = 0; j < 4; ++j) acc[i][j] = {0.f, 0.f, 0.f, 0.f};

  // prologue: stage tile 0 into buf 0
#pragma unroll
  for (int q = 0; q < 2; ++q) {
    int rb = (wave * 2 + q) * 16;
    gld_lds16(&A[(size_t)(m0 + rb + lrow) * K + lcol], &As[0][rb][0]);
    gld_lds16(&BT[(size_t)(n0 + rb + lrow) * K + lcol], &Bs[0][rb][0]);
  }
  __syncthreads();  // drains vmcnt(0): tile 0 ready

  int cur = 0;
  for (int kt = 32; kt < K; kt += 32) {
    // prefetch next tile into the other buffer
#pragma unroll
    for (int q = 0; q < 2; ++q) {
      int rb = (wave * 2 + q) * 16;
      gld_lds16(&A[(size_t)(m0 + rb + lrow) * K + kt + lcol],
                &As[cur ^ 1][rb][0]);
      gld_lds16(&BT[(size_t)(n0 + rb + lrow) * K + kt + lcol],
                &Bs[cur ^ 1][rb][0]);
    }
    // compute current tile (prefetch latency hides under this)
    bfrag8 af[4], bq[4];
#pragma unroll
    for (int i = 0; i < 4; ++i) {
      af[i] = *(const bfrag8*)&As[cur][wm + i * 16 + r16][quad * 8];
      bq[i] = *(const bfrag8*)&Bs[cur][wn + i * 16 + r16][quad * 8];
    }
#pragma unroll
    for (int i = 0; i < 4; ++i)
#pragma unroll
      for (int j = 0; j < 4; ++j)
        acc[i][j] = __builtin_amdgcn_mfma_f32_16x16x32_bf16(af[i], bq[j],
                                                            acc[i][j], 0, 0, 0);
    __syncthreads();  // full drain: next tile staged, reads of cur done
    cur ^= 1;
  }
  // epilogue tile (no prefetch)
  {
    bfrag8 af[4], bq[4];
#pragma unroll
    for (int i = 0; i < 4; ++i) {
      af[i] = *(const bfrag8*)&As[cur][wm + i * 16 + r16][quad * 8];
      bq[i] = *(const bfrag8*)&Bs[cur][wn + i * 16 + r16][quad * 8];
    }
#pragma unroll
    for (int i = 0; i < 4; ++i)
#pragma unroll
      for (int j = 0; j < 4; ++j)
        acc[i][j] = __builtin_amdgcn_mfma_f32_16x16x32_bf16(af[i], bq[j],
                                                            acc[i][j], 0, 0, 0);
  }
  bool gates = (n0 >= 5120);  // block-uniform (ni == 40)
#pragma unroll
  for (int i = 0; i < 4; ++i) {
#pragma unroll
    for (int r = 0; r < 4; ++r) {
      int row = m0 + wm + i * 16 + quad * 4 + r;
#pragma unroll
      for (int j = 0; j < 4; ++j) {
        int col = n0 + wn + j * 16 + r16;
        if (!gates)
          PALL[(size_t)row * PSA + col] = f2bf(acc[i][j][r]);
        else
          SPRJ[(size_t)row * 128 + col - 5120] = acc[i][j][r];
      }
    }
  }
}

// ---------------------------------------------------------------------------
// Fused knorm+gates: blocks 0..16383 knorm (L2-norm k rows in PALL);
// 16384..17407 gates (sigmoid+bias+marker, head-mean).
// ---------------------------------------------------------------------------
__global__ __launch_bounds__(256) void ng_kernel(
    unsigned short* __restrict__ pall, const float* __restrict__ SPRJ,
    const float* __restrict__ bb, const float* __restrict__ bg,
    const float* __restrict__ bgt, const int* __restrict__ ids,
    float* __restrict__ beta, float* __restrict__ g, float* __restrict__ mg) {
  int f = blockIdx.x;
  if (f < 16384) {
    int w = f * 4 + (threadIdx.x >> 6);  // (b*T+t)*H + h
    int lane = threadIdx.x & 63;
    size_t addr = (size_t)(w >> 4) * PSA + (w & 15) * 64 + lane;
    float v = bf2f(pall[addr]);
    float ss = v * v;
#pragma unroll
    for (int off = 32; off; off >>= 1) ss += __shfl_xor(ss, off);
    float n = sqrtf(ss);
    n = fmaxf(n, 1e-12f);
    pall[addr] = f2bf(v / n);
  } else {
    int row = (f - 16384) * 4 + (threadIdx.x >> 6);
    int lane = threadIdx.x & 63;
    if (lane < 48) {
      int h = lane & 15;
      float v = SPRJ[(size_t)row * 128 + lane];
      float bias = (lane < 16) ? bb[h] : (lane < 32) ? bg[h] : bgt[h];
      float s = 1.f / (1.f + __expf(-(v + bias)));
      if (lane < 16) {
        float mk = (ids[row] == MARKER_ID) ? 1.f : 0.1f;
        beta[(size_t)row * 16 + h] = s * mk;
      } else if (lane < 32) {
        g[(size_t)row * 16 + h] = s;
      } else {
        float sum = s;
#pragma unroll
        for (int off = 1; off < 16; off <<= 1) sum += __shfl_xor(sum, off);
        if (lane == 32) mg[row] = sum * (1.f / 16.f);
      }
    }
  }
}

// ---------------------------------------------------------------------------
// Scan phase A (per (bh,chunk)): M, u_free, Z, P, Q, a. bf16 K/V from PALL.
// ---------------------------------------------------------------------------
__global__ __launch_bounds__(256) void scan_phaseA(
    const unsigned short* __restrict__ PALL, const float* __restrict__ beta,
    const float* __restrict__ g, unsigned short* __restrict__ UFg,
    unsigned short* __restrict__ Zg, unsigned short* __restrict__ Pg,
    unsigned short* __restrict__ Qg, float* __restrict__ Ag) {
  __shared__ unsigned short Kc[64][72];
  __shared__ unsigned short KTb[64][72];
  __shared__ float Vc[64][68];
  __shared__ float Msv[64][68];
  __shared__ unsigned short UFT[64][72];
  __shared__ unsigned short ZTl[64][72];
  __shared__ float aArr[64], iaArr[64], bArr[64], baArr[64], sKT[64];
  __shared__ float aCs;

  int c = blockIdx.x, bh = blockIdx.y;
  int b = bh >> 4, h = bh & 15;
  int tc = c * 64;
  int tid = threadIdx.x, lane = tid & 63, wave = tid >> 6;
  int r16 = lane & 15, quad = lane >> 4;
  int m0w = wave * 16;
  size_t bhc = (size_t)bh * 16 + c;

  const unsigned short* kbase = PALL + ((size_t)b * TT) * PSA + h * 64;
  const unsigned short* vbase = kbase + 1024;
  const float* bbase = beta + ((size_t)b * TT) * HH + h;
  const float* gbase = g + ((size_t)b * TT) * HH + h;

  if (tid < 64) {
    int ts = tc + tid;
    bool pad = (ts > 1022);
    float gv = pad ? 1.f : gbase[(size_t)ts * HH];
    float bv = pad ? 0.f : bbase[(size_t)ts * HH];
    float p = gv;
#pragma unroll
    for (int o = 1; o < 64; o <<= 1) {
      float t = __shfl_up(p, o);
      if (lane >= o) p *= t;
    }
    aArr[tid] = p;
    iaArr[tid] = 1.f / p;
    bArr[tid] = bv;
    baArr[tid] = bv * p;
    float aC = __shfl(p, 63);
    sKT[tid] = aC / p;
    if (tid == 0) aCs = aC;
    Ag[bhc * 64 + tid] = p;
  }
  __syncthreads();
  {
    int r = tid >> 2, q = tid & 3;
    int ts = tc + r;
    float skt = sKT[r];
    union { uint4 u4[2]; unsigned short s[16]; } kv;
    kv.u4[0] = *(const uint4*)&kbase[(size_t)ts * PSA + q * 16];
    kv.u4[1] = *(const uint4*)&kbase[(size_t)ts * PSA + q * 16 + 8];
    *(uint4*)&Kc[r][q * 16] = kv.u4[0];
    *(uint4*)&Kc[r][q * 16 + 8] = kv.u4[1];
#pragma unroll
    for (int i = 0; i < 16; ++i)
      KTb[q * 16 + i][r] = f2bf(bf2f(kv.s[i]) * skt);
    if (ts <= 1022) {
      union { uint4 u4[2]; unsigned short s[16]; } vv;
      vv.u4[0] = *(const uint4*)&vbase[(size_t)(ts + 1) * PSA + q * 16];
      vv.u4[1] = *(const uint4*)&vbase[(size_t)(ts + 1) * PSA + q * 16 + 8];
#pragma unroll
      for (int i = 0; i < 16; ++i) Vc[r][q * 16 + i] = bf2f(vv.s[i]);
    } else {
#pragma unroll
      for (int i = 0; i < 16; ++i) Vc[r][q * 16 + i] = 0.f;
    }
  }
  __syncthreads();
  {
    bfrag8 af0 = *(const bfrag8*)&Kc[m0w + r16][quad * 8];
    bfrag8 af1 = *(const bfrag8*)&Kc[m0w + r16][quad * 8 + 32];
    f32x4 acc1[4];
#pragma unroll
    for (int j = 0; j < 4; ++j) acc1[j] = {0.f, 0.f, 0.f, 0.f};
#pragma unroll
    for (int j = 0; j < 4; ++j) {
      bfrag8 k0 = *(const bfrag8*)&Kc[j * 16 + r16][quad * 8];
      bfrag8 k1 = *(const bfrag8*)&Kc[j * 16 + r16][quad * 8 + 32];
      acc1[j] = __builtin_amdgcn_mfma_f32_16x16x32_bf16(af0, k0, acc1[j], 0, 0, 0);
      acc1[j] = __builtin_amdgcn_mfma_f32_16x16x32_bf16(af1, k1, acc1[j], 0, 0, 0);
    }
#pragma unroll
    for (int j = 0; j < 4; ++j) {
#pragma unroll
      for (int r = 0; r < 4; ++r) {
        int row = m0w + quad * 4 + r;
        int col = j * 16 + r16;
        Msv[row][col] =
            (col < row) ? bArr[row] * aArr[row] * iaArr[col] * acc1[j][r] : 0.f;
      }
    }
  }
  __syncthreads();
  if (wave < 2) {
    float u[64];
    if (wave == 0) {
#pragma unroll
      for (int t = 0; t < 64; ++t) u[t] = bArr[t] * Vc[t][lane];
    } else {
#pragma unroll
      for (int t = 0; t < 64; ++t) u[t] = baArr[t] * bf2f(Kc[t][lane]);
    }
#pragma unroll
    for (int t = 1; t < 64; ++t) {
      float a0 = 0.f, a1 = 0.f, a2 = 0.f, a3 = 0.f;
#pragma unroll
      for (int s4 = 0; s4 * 4 < t; ++s4) {
        float4 mr = *(const float4*)&Msv[t][s4 * 4];
        a0 = fmaf(mr.x, u[s4 * 4 + 0], a0);
        a1 = fmaf(mr.y, u[s4 * 4 + 1], a1);
        a2 = fmaf(mr.z, u[s4 * 4 + 2], a2);
        a3 = fmaf(mr.w, u[s4 * 4 + 3], a3);
      }
      u[t] -= (a0 + a1) + (a2 + a3);
    }
    unsigned short* Tls = (wave == 0) ? &UFT[lane][0] : &ZTl[lane][0];
#pragma unroll
    for (int t2 = 0; t2 < 32; ++t2) {
      unsigned int pk = (unsigned int)f2bf(u[2 * t2]) |
                        ((unsigned int)f2bf(u[2 * t2 + 1]) << 16);
      *(unsigned int*)&Tls[2 * t2] = pk;
    }
    unsigned short* Gn = (wave == 0) ? UFg : Zg;
#pragma unroll
    for (int t = 0; t < 64; ++t) {
      Gn[(bhc * 64 + t) * 64 + lane] = f2bf(u[t]);
    }
  }
  __syncthreads();
  {
    bfrag8 af0 = *(const bfrag8*)&KTb[m0w + r16][quad * 8];
    bfrag8 af1 = *(const bfrag8*)&KTb[m0w + r16][quad * 8 + 32];
    f32x4 accp[4], accq[4];
#pragma unroll
    for (int j = 0; j < 4; ++j) {
      accp[j] = {0.f, 0.f, 0.f, 0.f};
      accq[j] = {0.f, 0.f, 0.f, 0.f};
    }
#pragma unroll
    for (int j = 0; j < 4; ++j) {
      bfrag8 z0 = *(const bfrag8*)&ZTl[j * 16 + r16][quad * 8];
      bfrag8 z1 = *(const bfrag8*)&ZTl[j * 16 + r16][quad * 8 + 32];
      accp[j] = __builtin_amdgcn_mfma_f32_16x16x32_bf16(af0, z0, accp[j], 0, 0, 0);
      accp[j] = __builtin_amdgcn_mfma_f32_16x16x32_bf16(af1, z1, accp[j], 0, 0, 0);
      bfrag8 u0 = *(const bfrag8*)&UFT[j * 16 + r16][quad * 8];
      bfrag8 u1 = *(const bfrag8*)&UFT[j * 16 + r16][quad * 8 + 32];
      accq[j] = __builtin_amdgcn_mfma_f32_16x16x32_bf16(af0, u0, accq[j], 0, 0, 0);
      accq[j] = __builtin_amdgcn_mfma_f32_16x16x32_bf16(af1, u1, accq[j], 0, 0, 0);
    }
    float aC = aCs;
#pragma unroll
    for (int j = 0; j < 4; ++j) {
#pragma unroll
      for (int r = 0; r < 4; ++r) {
        int row = m0w + quad * 4 + r;
        int col = j * 16 + r16;
        float pv = ((row == col) ? aC : 0.f) - accp[j][r];
        Pg[bhc * 4096 + (size_t)row * 64 + col] = f2bf(pv);
        Qg[bhc * 4096 + (size_t)row * 64 + col] = f2bf(accq[j][r]);
      }
    }
  }
}

// ---------------------------------------------------------------------------
// Scan phase B: serial S_{c+1} = P_c S_c + Q_c.
// ---------------------------------------------------------------------------
__global__ __launch_bounds__(256) void scan_phaseB(
    const float* __restrict__ S0, const unsigned short* __restrict__ Pg,
    const unsigned short* __restrict__ Qg, unsigned short* __restrict__ SinTg,
    float* __restrict__ Sf, unsigned short* __restrict__ ACAT) {
  __shared__ unsigned short STb[64][72];
  __shared__ unsigned short Pl[64][72];
  int bh = blockIdx.x;
  int b = bh >> 4, h = bh & 15;
  int tid = threadIdx.x, lane = tid & 63, wave = tid >> 6;
  int r16 = lane & 15, quad = lane >> 4;
  int m0w = wave * 16;
  int rr = tid >> 2, qq = tid & 3;
  {
    const float* s0p = S0 + (size_t)bh * 4096;
#pragma unroll
    for (int i = 0; i < 4; ++i) {
      float4 sv = *(const float4*)&s0p[rr * 64 + qq * 16 + i * 4];
      STb[qq * 16 + i * 4 + 0][rr] = f2bf(sv.x);
      STb[qq * 16 + i * 4 + 1][rr] = f2bf(sv.y);
      STb[qq * 16 + i * 4 + 2][rr] = f2bf(sv.z);
      STb[qq * 16 + i * 4 + 3][rr] = f2bf(sv.w);
    }
    if (tid < 64) ACAT[((size_t)b * TT) * PSB + h * 64 + tid] = 0;
  }
  for (int c = 0; c < 16; ++c) {
    size_t bhc = (size_t)bh * 16 + c;
    __syncthreads();
    {
      uint4 s0v = *(const uint4*)&STb[rr][qq * 16];
      uint4 s1v = *(const uint4*)&STb[rr][qq * 16 + 8];
      *(uint4*)&SinTg[bhc * 4096 + (size_t)rr * 64 + qq * 16] = s0v;
      *(uint4*)&SinTg[bhc * 4096 + (size_t)rr * 64 + qq * 16 + 8] = s1v;
      uint4 p0 = *(const uint4*)&Pg[bhc * 4096 + (size_t)rr * 64 + qq * 16];
      uint4 p1 = *(const uint4*)&Pg[bhc * 4096 + (size_t)rr * 64 + qq * 16 + 8];
      *(uint4*)&Pl[rr][qq * 16] = p0;
      *(uint4*)&Pl[rr][qq * 16 + 8] = p1;
    }
    __syncthreads();
    f32x4 acc[4];
#pragma unroll
    for (int j = 0; j < 4; ++j) acc[j] = {0.f, 0.f, 0.f, 0.f};
    {
      bfrag8 af0 = *(const bfrag8*)&Pl[m0w + r16][quad * 8];
      bfrag8 af1 = *(const bfrag8*)&Pl[m0w + r16][quad * 8 + 32];
#pragma unroll
      for (int j = 0; j < 4; ++j) {
        bfrag8 s0v = *(const bfrag8*)&STb[j * 16 + r16][quad * 8];
        bfrag8 s1v = *(const bfrag8*)&STb[j * 16 + r16][quad * 8 + 32];
        acc[j] = __builtin_amdgcn_mfma_f32_16x16x32_bf16(af0, s0v, acc[j], 0, 0, 0);
        acc[j] = __builtin_amdgcn_mfma_f32_16x16x32_bf16(af1, s1v, acc[j], 0, 0, 0);
      }
    }
    float snew[4][4];
#pragma unroll
    for (int j = 0; j < 4; ++j) {
#pragma unroll
      for (int r = 0; r < 4; ++r) {
        int row = m0w + quad * 4 + r;
        int col = j * 16 + r16;
        snew[j][r] = acc[j][r] + bf2f(Qg[bhc * 4096 + (size_t)row * 64 + col]);
      }
    }
    __syncthreads();
#pragma unroll
    for (int j = 0; j < 4; ++j) {
#pragma unroll
      for (int r = 0; r < 4; ++r) {
        int row = m0w + quad * 4 + r;
        int col = j * 16 + r16;
        STb[col][row] = f2bf(snew[j][r]);
        if (c == 15) Sf[(size_t)bh * 4096 + (size_t)row * 64 + col] = snew[j][r];
      }
    }
  }
}

// ---------------------------------------------------------------------------
// Fused tail: attn (1024) + scanC (1024) + retrieve (1024), round-robin
// interleave (bx%3). Union LDS 37.4KB -> 4 blocks/CU; launch_bounds(256,4)
// caps regs at 128. attn=MFMA-heavy, scanC=mixed, retrieve=memory -> the
// mix overlaps pipes per CU (m114 MFMA||VALU co-scheduling).
// ---------------------------------------------------------------------------
union SmF {
  struct { unsigned short Qs[64][72], Ks[64][72], Vt[64][72], Ps[64][72]; } at;
  struct {
    unsigned short Kc[64][72], SvT[64][72], Wl[64][72], UTl[64][72];
    float aA[64], iaA[64];
  } sc;
  struct { float Sfs[64][64]; } rt;
};

static __device__ void attn_body(int qi, const unsigned short* __restrict__ PALL,
                                 unsigned short* __restrict__ ACAT, SmF& sm) {
  auto& Qs = sm.at.Qs;
  auto& Ks = sm.at.Ks;
  auto& Vt = sm.at.Vt;
  auto& Ps = sm.at.Ps;
  int qb = (qi & 15) * 64;
  int bh = qi >> 4;
  int h = bh & 15, b = bh >> 4;
  int tid = threadIdx.x, lane = tid & 63, wave = tid >> 6;
  int r16 = lane & 15, quad = lane >> 4;
  int m0w = wave * 16;
  const unsigned short* Qg = PALL + (size_t)b * TT * PSA + 2048 + h * 64;
  const unsigned short* Kg = Qg + 1024;
  const unsigned short* Vg = Qg + 2048;
  int sr = tid >> 2, sq = tid & 3;
  int kt0 = qb - (int)WIN;
  if (kt0 < 0) kt0 = 0;

  uint4 kr0, kr1;
  union { uint4 u4[2]; unsigned short s[16]; } vr;
  {
    *(uint4*)&Qs[sr][sq * 16] =
        *(const uint4*)&Qg[(size_t)(qb + sr) * PSA + sq * 16];
    *(uint4*)&Qs[sr][sq * 16 + 8] =
        *(const uint4*)&Qg[(size_t)(qb + sr) * PSA + sq * 16 + 8];
    kr0 = *(const uint4*)&Kg[(size_t)(kt0 + sr) * PSA + sq * 16];
    kr1 = *(const uint4*)&Kg[(size_t)(kt0 + sr) * PSA + sq * 16 + 8];
    vr.u4[0] = *(const uint4*)&Vg[(size_t)(kt0 + sr) * PSA + sq * 16];
    vr.u4[1] = *(const uint4*)&Vg[(size_t)(kt0 + sr) * PSA + sq * 16 + 8];
  }
  __syncthreads();  // Qs visible
  bfrag8 af0 = *(const bfrag8*)&Qs[m0w + r16][quad * 8];
  bfrag8 af1 = *(const bfrag8*)&Qs[m0w + r16][quad * 8 + 32];
  {
    *(uint4*)&Ks[sr][sq * 16] = kr0;
    *(uint4*)&Ks[sr][sq * 16 + 8] = kr1;
#pragma unroll
    for (int i = 0; i < 16; ++i) Vt[sq * 16 + i][sr] = vr.s[i];
  }
  __syncthreads();  // Ks/Vt visible

  float m[4], l[4];
  f32x4 o[4];
#pragma unroll
  for (int r = 0; r < 4; ++r) {
    m[r] = -1e30f;
    l[r] = 0.f;
    o[r] = {0.f, 0.f, 0.f, 0.f};
  }

  for (int kt = kt0; kt <= qb; kt += 64) {
    bool more = (kt + 64 <= qb);
    if (more) {
      kr0 = *(const uint4*)&Kg[(size_t)(kt + 64 + sr) * PSA + sq * 16];
      kr1 = *(const uint4*)&Kg[(size_t)(kt + 64 + sr) * PSA + sq * 16 + 8];
      vr.u4[0] = *(const uint4*)&Vg[(size_t)(kt + 64 + sr) * PSA + sq * 16];
      vr.u4[1] = *(const uint4*)&Vg[(size_t)(kt + 64 + sr) * PSA + sq * 16 + 8];
    }
    f32x4 s[4];
#pragma unroll
    for (int j = 0; j < 4; ++j) s[j] = {0.f, 0.f, 0.f, 0.f};
#pragma unroll
    for (int j = 0; j < 4; ++j) {
      bfrag8 b0 = *(const bfrag8*)&Ks[j * 16 + r16][quad * 8];
      bfrag8 b1 = *(const bfrag8*)&Ks[j * 16 + r16][quad * 8 + 32];
      s[j] = __builtin_amdgcn_mfma_f32_16x16x32_bf16(af0, b0, s[j], 0, 0, 0);
      s[j] = __builtin_amdgcn_mfma_f32_16x16x32_bf16(af1, b1, s[j], 0, 0, 0);
    }
    bool oldest = (kt == qb - (int)WIN);
    bool newest = (kt == qb);
#pragma unroll
    for (int r = 0; r < 4; ++r) {
      int il = m0w + quad * 4 + r;
      float sv[4];
#pragma unroll
      for (int j = 0; j < 4; ++j) {
        int jl = j * 16 + r16;
        float v = s[j][r] * 0.125f;
        if (oldest && jl < il) v = -1e30f;
        if (newest && jl > il) v = -1e30f;
        sv[j] = v;
      }
      float mx = fmaxf(fmaxf(sv[0], sv[1]), fmaxf(sv[2], sv[3]));
#pragma unroll
      for (int off = 1; off < 16; off <<= 1) mx = fmaxf(mx, __shfl_xor(mx, off));
      float mn = fmaxf(m[r], mx);
      float al = __expf(m[r] - mn);
      m[r] = mn;
      float rs = 0.f;
#pragma unroll
      for (int j = 0; j < 4; ++j) {
        float p = __expf(sv[j] - mn);
        rs += p;
        Ps[il][j * 16 + r16] = f2bf(p);
      }
#pragma unroll
      for (int off = 1; off < 16; off <<= 1) rs += __shfl_xor(rs, off);
      l[r] = l[r] * al + rs;
#pragma unroll
      for (int j = 0; j < 4; ++j) o[j][r] *= al;
    }
    bfrag8 pa0 = *(const bfrag8*)&Ps[m0w + r16][quad * 8];
    bfrag8 pa1 = *(const bfrag8*)&Ps[m0w + r16][quad * 8 + 32];
#pragma unroll
    for (int j = 0; j < 4; ++j) {
      bfrag8 v0 = *(const bfrag8*)&Vt[j * 16 + r16][quad * 8];
      bfrag8 v1 = *(const bfrag8*)&Vt[j * 16 + r16][quad * 8 + 32];
      o[j] = __builtin_amdgcn_mfma_f32_16x16x32_bf16(pa0, v0, o[j], 0, 0, 0);
      o[j] = __builtin_amdgcn_mfma_f32_16x16x32_bf16(pa1, v1, o[j], 0, 0, 0);
    }
    if (more) {
      __syncthreads();  // all waves done reading Ks/Vt
      *(uint4*)&Ks[sr][sq * 16] = kr0;
      *(uint4*)&Ks[sr][sq * 16 + 8] = kr1;
#pragma unroll
      for (int i = 0; i < 16; ++i) Vt[sq * 16 + i][sr] = vr.s[i];
      __syncthreads();  // next tile visible
    }
  }
#pragma unroll
  for (int r = 0; r < 4; ++r) {
    int row = m0w + quad * 4 + r;
    float inv = 1.f / l[r];
#pragma unroll
    for (int j = 0; j < 4; ++j) {
      ACAT[((size_t)(b * TT + qb + row)) * PSB + 1024 + h * 64 + j * 16 + r16] =
          f2bf(o[j][r] * inv);
    }
  }
}

static __device__ void scanC_body(
    int c, int bh, const unsigned short* __restrict__ PALL,
    const unsigned short* __restrict__ UFg,
    const unsigned short* __restrict__ Zg,
    const unsigned short* __restrict__ SinTg, const float* __restrict__ Ag,
    unsigned short* __restrict__ ACAT, SmF& sm) {
  auto& Kc = sm.sc.Kc;
  auto& SvT = sm.sc.SvT;
  auto& Wl = sm.sc.Wl;
  auto& UTl = sm.sc.UTl;
  auto& aA = sm.sc.aA;
  auto& iaA = sm.sc.iaA;

  int b = bh >> 4, h = bh & 15;
  int tc = c * 64;
  int tid = threadIdx.x, lane = tid & 63, wave = tid >> 6;
  int r16 = lane & 15, quad = lane >> 4;
  int m0w = wave * 16;
  size_t bhc = (size_t)bh * 16 + c;
  const unsigned short* kbase = PALL + ((size_t)b * TT) * PSA + h * 64;

  if (tid < 64) {
    float av = Ag[bhc * 64 + tid];
    aA[tid] = av;
    iaA[tid] = 1.f / av;
  }
  {
    int r = tid >> 2, q = tid & 3;
    int ts = tc + r;
    *(uint4*)&Kc[r][q * 16] = *(const uint4*)&kbase[(size_t)ts * PSA + q * 16];
    *(uint4*)&Kc[r][q * 16 + 8] =
        *(const uint4*)&kbase[(size_t)ts * PSA + q * 16 + 8];
    uint4 sv0 = *(const uint4*)&SinTg[bhc * 4096 + (size_t)r * 64 + q * 16];
    uint4 sv1 = *(const uint4*)&SinTg[bhc * 4096 + (size_t)r * 64 + q * 16 + 8];
    *(uint4*)&SvT[r][q * 16] = sv0;
    *(uint4*)&SvT[r][q * 16 + 8] = sv1;
  }
  // Z fragments direct from global (A-operand layout: row m0w+r16)
  bfrag8 zf0 = *(const bfrag8*)&Zg[(bhc * 64 + m0w + r16) * 64 + quad * 8];
  bfrag8 zf1 =
      *(const bfrag8*)&Zg[(bhc * 64 + m0w + r16) * 64 + quad * 8 + 32];
  __syncthreads();
  float op[4][4];
  {
    bfrag8 af0 = *(const bfrag8*)&Kc[m0w + r16][quad * 8];
    bfrag8 af1 = *(const bfrag8*)&Kc[m0w + r16][quad * 8 + 32];
    f32x4 acc1[4], acc2[4], acc3[4];
#pragma unroll
    for (int j = 0; j < 4; ++j) {
      acc1[j] = {0.f, 0.f, 0.f, 0.f};
      acc2[j] = {0.f, 0.f, 0.f, 0.f};
      acc3[j] = {0.f, 0.f, 0.f, 0.f};
    }
#pragma unroll
    for (int j = 0; j < 4; ++j) {
      bfrag8 k0 = *(const bfrag8*)&Kc[j * 16 + r16][quad * 8];
      bfrag8 k1 = *(const bfrag8*)&Kc[j * 16 + r16][quad * 8 + 32];
      acc1[j] = __builtin_amdgcn_mfma_f32_16x16x32_bf16(af0, k0, acc1[j], 0, 0, 0);
      acc1[j] = __builtin_amdgcn_mfma_f32_16x16x32_bf16(af1, k1, acc1[j], 0, 0, 0);
      bfrag8 s0 = *(const bfrag8*)&SvT[j * 16 + r16][quad * 8];
      bfrag8 s1 = *(const bfrag8*)&SvT[j * 16 + r16][quad * 8 + 32];
      acc3[j] = __builtin_amdgcn_mfma_f32_16x16x32_bf16(af0, s0, acc3[j], 0, 0, 0);
      acc3[j] = __builtin_amdgcn_mfma_f32_16x16x32_bf16(af1, s1, acc3[j], 0, 0, 0);
      acc2[j] = __builtin_amdgcn_mfma_f32_16x16x32_bf16(zf0, s0, acc2[j], 0, 0, 0);
      acc2[j] = __builtin_amdgcn_mfma_f32_16x16x32_bf16(zf1, s1, acc2[j], 0, 0, 0);
    }
#pragma unroll
    for (int j = 0; j < 4; ++j) {
#pragma unroll
      for (int r = 0; r < 4; ++r) {
        int row = m0w + quad * 4 + r;
        int col = j * 16 + r16;
        Wl[row][col] = (col <= row) ? f2bf(aA[row] * iaA[col] * acc1[j][r])
                                    : (unsigned short)0;
        float uval = bf2f(UFg[(bhc * 64 + row) * 64 + col]) - acc2[j][r];
        UTl[col][row] = f2bf(uval);
        op[j][r] = aA[row] * acc3[j][r];
      }
    }
  }
  __syncthreads();
  {
    bfrag8 wf0 = *(const bfrag8*)&Wl[m0w + r16][quad * 8];
    bfrag8 wf1 = *(const bfrag8*)&Wl[m0w + r16][quad * 8 + 32];
    f32x4 acc4[4];
#pragma unroll
    for (int j = 0; j < 4; ++j) acc4[j] = {0.f, 0.f, 0.f, 0.f};
#pragma unroll
    for (int j = 0; j < 4; ++j) {
      bfrag8 u0 = *(const bfrag8*)&UTl[j * 16 + r16][quad * 8];
      bfrag8 u1 = *(const bfrag8*)&UTl[j * 16 + r16][quad * 8 + 32];
      acc4[j] = __builtin_amdgcn_mfma_f32_16x16x32_bf16(wf0, u0, acc4[j], 0, 0, 0);
      acc4[j] = __builtin_amdgcn_mfma_f32_16x16x32_bf16(wf1, u1, acc4[j], 0, 0, 0);
    }
#pragma unroll
    for (int j = 0; j < 4; ++j) {
#pragma unroll
      for (int r = 0; r < 4; ++r) {
        int row = m0w + quad * 4 + r;
        int col = j * 16 + r16;
        int ts = tc + row;
        if (ts < 1023) {
          ACAT[((size_t)b * TT + ts + 1) * PSB + h * 64 + col] =
              f2bf(op[j][r] + acc4[j][r]);
        }
      }
    }
  }
}

static __device__ void retrieve_body(
    int cx, int bh, const unsigned short* __restrict__ PALL,
    const float* __restrict__ Sf, const float* __restrict__ mg,
    unsigned short* __restrict__ ACAT, SmF& sm) {
  auto& Sfs = sm.rt.Sfs;
  int tc = cx * 64;
  int b = bh >> 4, h = bh & 15;
  int tid = threadIdx.x, lane = tid & 63, wave = tid >> 6;
  const float* sfp = Sf + (size_t)bh * 4096;
#pragma unroll
  for (int i = 0; i < 4; ++i) {
    int e = tid + i * 256;  // float4 index 0..1023
    ((float4*)&Sfs[0][0])[e] = ((const float4*)sfp)[e];
  }
  __syncthreads();
  const unsigned short* kb = PALL + ((size_t)b * TT) * PSA + h * 64;
#pragma unroll 2
  for (int ti = 0; ti < 16; ++ti) {
    int t = tc + wave * 16 + ti;
    size_t bt = (size_t)b * TT + t;
    float kl = bf2f(kb[(size_t)t * PSA + lane]);  // lane = k (coalesced)
    float a0 = 0.f, a1 = 0.f, a2 = 0.f, a3 = 0.f;
#pragma unroll
    for (int k = 0; k < 64; k += 4) {
      a0 = fmaf(__shfl(kl, k + 0), Sfs[k + 0][lane], a0);
      a1 = fmaf(__shfl(kl, k + 1), Sfs[k + 1][lane], a1);
      a2 = fmaf(__shfl(kl, k + 2), Sfs[k + 2][lane], a2);
      a3 = fmaf(__shfl(kl, k + 3), Sfs[k + 3][lane], a3);
    }
    float acc = (a0 + a1) + (a2 + a3);
    ACAT[bt * PSB + 2048 + h * 64 + lane] = f2bf(acc * mg[bt]);
  }
}

__global__ __launch_bounds__(256, 4) void tail3_kernel(
    const unsigned short* __restrict__ PALL,
    const unsigned short* __restrict__ UFg,
    const unsigned short* __restrict__ Zg,
    const unsigned short* __restrict__ SinTg, const float* __restrict__ Ag,
    const float* __restrict__ Sf, const float* __restrict__ mg,
    unsigned short* __restrict__ ACAT) {
  __shared__ SmF sm;
  int bx = blockIdx.x;     // 0..3071
  int type = bx % 3;       // round-robin: mix pipes per CU
  int idx = bx / 3;        // 0..1023
  if (type == 0) {
    attn_body(idx, PALL, ACAT, sm);
  } else if (type == 1) {
    scanC_body(idx & 15, idx >> 4, PALL, UFg, Zg, SinTg, Ag, ACAT, sm);
  } else {
    retrieve_body(idx & 15, idx >> 4, PALL, Sf, mg, ACAT, sm);
  }
}

// ---------------------------------------------------------------------------
extern "C" void kernel_launch(void* const* d_in, const int* in_sizes, int n_in,
                              void* d_out, int out_size, void* d_ws,
                              size_t ws_size, hipStream_t stream) {
  (void)in_sizes; (void)n_in; (void)out_size; (void)ws_size;
  const float* x       = (const float*)d_in[0];
  const float* S0      = (const float*)d_in[1];
  const float* W_k     = (const float*)d_in[2];
  const float* W_v     = (const float*)d_in[3];
  const float* W_gdn_o = (const float*)d_in[4];
  const float* W_beta  = (const float*)d_in[5];
  const float* b_beta  = (const float*)d_in[6];
  const float* W_g     = (const float*)d_in[7];
  const float* b_g     = (const float*)d_in[8];
  const float* W_lq    = (const float*)d_in[9];
  const float* W_lk    = (const float*)d_in[10];
  const float* W_lv    = (const float*)d_in[11];
  const float* W_swa_o = (const float*)d_in[12];
  const float* W_ret_o = (const float*)d_in[13];
  const float* W_gate  = (const float*)d_in[14];
  const float* b_gate  = (const float*)d_in[15];
  const float* norm_w  = (const float*)d_in[16];
  const int*   ids     = (const int*)d_in[17];
  float* out = (float*)d_out;

  char* ws = (char*)d_ws;
  size_t off = 0;
  auto allocf = [&](size_t n) {
    float* p = (float*)(ws + off);
    off += n * sizeof(float);
    return p;
  };
  auto allocu = [&](size_t n) {
    unsigned short* p = (unsigned short*)(ws + off);
    off += n * sizeof(unsigned short);
    return p;
  };
  const int M = BB * TT;  // 4096
  unsigned short* XNb    = allocu((size_t)M * DD);
  unsigned short* PALL   = allocu((size_t)M * PSA);   // K|V|Q|KL|VL bf16
  unsigned short* ACAT   = allocu((size_t)M * PSB);   // gdn | local | retr
  float*          SPRJ   = allocf((size_t)M * 128);   // gate logits
  unsigned short* WTcat5 = allocu((size_t)NPROJ * 1024);
  unsigned short* WTcat3 = allocu((size_t)1024 * PSB);
  float* BETA = allocf((size_t)M * HH);
  float* Gg   = allocf((size_t)M * HH);
  float* MG   = allocf((size_t)M);
  float* SF   = allocf((size_t)BB * HH * KK * VV);
  const size_t CH = (size_t)BB * HH * 16 * 64 * 64;
  unsigned short* UFg   = allocu(CH);
  unsigned short* Zg    = allocu(CH);
  unsigned short* Pg    = allocu(CH);
  unsigned short* Qg    = allocu(CH);
  unsigned short* SinTg = allocu(CH);
  float* Ag = allocf((size_t)BB * HH * 16 * 64);

  // rmsnorm (4096 blocks) + convert_wt (2304 blocks) fused
  prep_kernel<<<6400, 256, 0, stream>>>(x, norm_w, XNb, W_k, W_v, W_lq, W_lk,
                                        W_lv, W_gdn_o, W_swa_o, W_ret_o,
                                        W_beta, W_g, W_gate, WTcat5, WTcat3);

  gemm_proj_kernel<<<dim3(41, 32), 256, 0, stream>>>(XNb, WTcat5, PALL, SPRJ);

  // knorm (16384 blocks) + gates (1024 blocks) fused
  ng_kernel<<<17408, 256, 0, stream>>>(PALL, SPRJ, b_beta, b_g, b_gate, ids,
                                       BETA, Gg, MG);

  scan_phaseA<<<dim3(16, BB * HH), 256, 0, stream>>>(PALL, BETA, Gg, UFg, Zg,
                                                     Pg, Qg, Ag);
  scan_phaseB<<<BB * HH, 256, 0, stream>>>(S0, Pg, Qg, SinTg, SF, ACAT);

  // attn (1024) + scanC (1024) + retrieve (1024) fused, round-robin
  tail3_kernel<<<3072, 256, 0, stream>>>(PALL, UFg, Zg, SinTg, Ag, SF, MG,
                                         ACAT);

  // out = x + [gdn | local*0.3W | retr*mg] @ WTcat3^T  (K=3072, 512 blocks)
  gemm_out_kernel<<<dim3(16, 32), 256, 0, stream>>>(ACAT, WTcat3, out, x, M, DD,
                                                    3072);
}

// Round 11
// 378.349 us; speedup vs baseline: 1.2262x; 1.2262x over previous
//
#include <hip/hip_runtime.h>
#include <hip/hip_bf16.h>

// Problem constants
#define BB 4
#define TT 1024
#define DD 1024
#define HH 16
#define KK 64
#define VV 64
#define WIN 256
#define MARKER_ID 50251
#define PSA 5120   // bf16 all-proj row stride: K|V|Q|KL|VL
#define PSB 3072   // epilogue-cat row stride (gdn|local|retr)
#define NPROJ 5248 // proj GEMM N: 5120 bf16 + 128 gates(48+80 pad)

typedef short bfrag8 __attribute__((ext_vector_type(8)));
typedef float f32x4 __attribute__((ext_vector_type(4)));

static __device__ __forceinline__ unsigned short f2bf(float f) {
  __hip_bfloat16 h = __float2bfloat16(f);
  union { __hip_bfloat16 h; unsigned short u; } cv;
  cv.h = h;
  return cv.u;
}
static __device__ __forceinline__ float bf2f(unsigned short u) {
  union { unsigned int i; float f; } c;
  c.i = ((unsigned int)u) << 16;
  return c.f;
}
// Async global->LDS, 16B per lane. LDS dest = wave-uniform base + lane*16.
static __device__ __forceinline__ void gld_lds16(const unsigned short* g,
                                                 unsigned short* l) {
  __builtin_amdgcn_global_load_lds(
      (const __attribute__((address_space(1))) void*)g,
      (__attribute__((address_space(3))) void*)l, 16, 0, 0);
}

// ---------------------------------------------------------------------------
// RMSNorm body: xnb (bf16) = x / sqrt(mean(x^2)+eps) * norm_w. One block/row.
// ---------------------------------------------------------------------------
static __device__ __forceinline__ void rmsnorm_body(
    int row, const float* __restrict__ x, const float* __restrict__ nw,
    unsigned short* __restrict__ xnb, float* red) {
  int tid = threadIdx.x;
  const float4* xr = (const float4*)(x + (size_t)row * DD);
  float4 v = xr[tid];
  float ss = v.x * v.x + v.y * v.y + v.z * v.z + v.w * v.w;
#pragma unroll
  for (int off = 32; off; off >>= 1) ss += __shfl_xor(ss, off);
  int wid = tid >> 6;
  if ((tid & 63) == 0) red[wid] = ss;
  __syncthreads();
  float tot = red[0] + red[1] + red[2] + red[3];
  float inv = 1.0f / sqrtf(tot * (1.0f / DD) + 1e-6f);
  const float4* wr = (const float4*)nw;
  float4 wv = wr[tid];
  ushort4 o;
  o.x = f2bf(v.x * inv * wv.x);
  o.y = f2bf(v.y * inv * wv.y);
  o.z = f2bf(v.z * inv * wv.z);
  o.w = f2bf(v.w * inv * wv.w);
  *(ushort4*)&xnb[(size_t)row * DD + tid * 4] = o;
}

// ---------------------------------------------------------------------------
// Convert weights body: fp32 [K][N] -> bf16 [N][K] concatenated buffers.
// z=0..7: 1024x1024 weights. z=8: gate weights + zero-pad.
// ---------------------------------------------------------------------------
static __device__ __forceinline__ void convert_body(
    int xb, int yb, int zb, const float* W0, const float* W1, const float* W2,
    const float* W3, const float* W4, const float* W5, const float* W6,
    const float* W7, const float* Wb, const float* Wg, const float* Wgt,
    unsigned short* C5, unsigned short* C3, float (*Ts)[68]) {
  int tid = threadIdx.x;
  if (zb == 8) {
    if (xb != 0) return;
    int k0 = yb * 64;
    for (int e = tid; e < 3 * 16 * 64; e += 256) {
      int w = e >> 10;
      int h = (e >> 6) & 15;
      int kk = e & 63;
      const float* Ws = (w == 0) ? Wb : (w == 1) ? Wg : Wgt;
      C5[(size_t)(5120 + w * 16 + h) * 1024 + k0 + kk] =
          f2bf(Ws[(size_t)(k0 + kk) * 16 + h]);
    }
    for (int e = tid; e < 80 * 64; e += 256) {
      int r = e >> 6, kk = e & 63;
      C5[(size_t)(5168 + r) * 1024 + k0 + kk] = 0;
    }
    return;
  }
  const float* W;
  unsigned short* T;
  int stride;
  float scale = 1.f;
  switch (zb) {
    case 0: W = W0; T = C5 + 0 * 1024 * 1024; stride = 1024; break;
    case 1: W = W1; T = C5 + 1 * 1024 * 1024; stride = 1024; break;
    case 2: W = W2; T = C5 + 2 * 1024 * 1024; stride = 1024; break;
    case 3: W = W3; T = C5 + 3 * 1024 * 1024; stride = 1024; break;
    case 4: W = W4; T = C5 + 4 * 1024 * 1024; stride = 1024; break;
    case 5: W = W5; T = C3 + 0; stride = PSB; break;
    case 6: W = W6; T = C3 + 1024; stride = PSB; scale = 0.3f; break;
    default: W = W7; T = C3 + 2048; stride = PSB; break;
  }
  int n0 = xb * 64, k0 = yb * 64;
#pragma unroll
  for (int p = 0; p < 4; ++p) {
    int e = p * 256 + tid;
    int k = e >> 4, nq = e & 15;
    float4 w = *(const float4*)&W[(size_t)(k0 + k) * 1024 + n0 + nq * 4];
    Ts[nq * 4 + 0][k] = w.x;
    Ts[nq * 4 + 1][k] = w.y;
    Ts[nq * 4 + 2][k] = w.z;
    Ts[nq * 4 + 3][k] = w.w;
  }
  __syncthreads();
#pragma unroll
  for (int p = 0; p < 4; ++p) {
    int e = p * 256 + tid;
    int n = e >> 4, kq = e & 15;
    float4 v = *(const float4*)&Ts[n][kq * 4];
    ushort4 u;
    u.x = f2bf(v.x * scale);
    u.y = f2bf(v.y * scale);
    u.z = f2bf(v.z * scale);
    u.w = f2bf(v.w * scale);
    *(ushort4*)&T[(size_t)(n0 + n) * stride + k0 + kq * 4] = u;
  }
}

// ---------------------------------------------------------------------------
// Fused prep: blocks 0..4095 rmsnorm; 4096..6399 convert_wt (decode x,y,z).
// ---------------------------------------------------------------------------
__global__ __launch_bounds__(256) void prep_kernel(
    const float* __restrict__ x, const float* __restrict__ nw,
    unsigned short* __restrict__ xnb, const float* W0, const float* W1,
    const float* W2, const float* W3, const float* W4, const float* W5,
    const float* W6, const float* W7, const float* Wb, const float* Wg,
    const float* Wgt, unsigned short* C5, unsigned short* C3) {
  __shared__ __align__(16) float Ts[64][68];
  int f = blockIdx.x;
  if (f < 4096) {
    rmsnorm_body(f, x, nw, xnb, &Ts[0][0]);
  } else {
    int c = f - 4096;  // 0..2303 = 9 z * 16 y * 16 x
    convert_body(c & 15, (c >> 4) & 15, c >> 8, W0, W1, W2, W3, W4, W5, W6, W7,
                 Wb, Wg, Wgt, C5, C3, Ts);
  }
}

// ---------------------------------------------------------------------------
// Epilogue GEMM: out = x + ACAT[4096][3072] @ WTcat3[1024][3072]^T.
// 128M x 64N tile -> 512 blocks. XCD swizzle. Grid MUST be (16, 32).
// Counted-vmcnt 2-deep pipeline (R2 winner). __launch_bounds__(256,4):
// same occupancy lever as proj (R5: 77->68us) — cap regs <=128 for
// 4 blocks/CU on a latency-bound kernel (LDS 24KB allows 5).
// ---------------------------------------------------------------------------
__global__ __launch_bounds__(256, 4) void gemm_out_kernel(
    const unsigned short* __restrict__ A, const unsigned short* __restrict__ BT,
    float* __restrict__ C, const float* __restrict__ addp, int M, int N,
    int K) {
  __shared__ unsigned short As[2][128][32];
  __shared__ unsigned short Bs[2][64][32];
  int flat = blockIdx.y * gridDim.x + blockIdx.x;
  int xcd = flat & 7, local = flat >> 3;
  int m0 = (xcd * 4 + (local & 3)) * 128;
  int n0 = (local >> 2) * 64;
  int tid = threadIdx.x;
  int wave = tid >> 6, lane = tid & 63;
  int wm = wave * 32;
  int r16 = lane & 15, quad = lane >> 4;
  int lrow = lane >> 2, lcol = (lane & 3) * 8;

  f32x4 acc[2][4];
#pragma unroll
  for (int i = 0; i < 2; ++i)
#pragma unroll
    for (int j = 0; j < 4; ++j) acc[i][j] = {0.f, 0.f, 0.f, 0.f};

  auto STAGE = [&](int buf, int kt) {
#pragma unroll
    for (int q = 0; q < 2; ++q) {
      int rb = (wave * 2 + q) * 16;
      gld_lds16(&A[(size_t)(m0 + rb + lrow) * K + kt + lcol], &As[buf][rb][0]);
    }
    {
      int rb = wave * 16;
      gld_lds16(&BT[(size_t)(n0 + rb + lrow) * K + kt + lcol], &Bs[buf][rb][0]);
    }
  };
  auto COMPUTE = [&](int buf) {
    bfrag8 af[2], bq[4];
#pragma unroll
    for (int i = 0; i < 2; ++i)
      af[i] = *(const bfrag8*)&As[buf][wm + i * 16 + r16][quad * 8];
#pragma unroll
    for (int j = 0; j < 4; ++j)
      bq[j] = *(const bfrag8*)&Bs[buf][j * 16 + r16][quad * 8];
#pragma unroll
    for (int i = 0; i < 2; ++i)
#pragma unroll
      for (int j = 0; j < 4; ++j)
        acc[i][j] = __builtin_amdgcn_mfma_f32_16x16x32_bf16(af[i], bq[j],
                                                            acc[i][j], 0, 0, 0);
  };

  // prologue: 2 tiles in flight (3 loads/wave each)
  STAGE(0, 0);
  STAGE(1, 32);
  asm volatile("s_waitcnt vmcnt(3)" ::: "memory");  // tile 0 landed
  __builtin_amdgcn_s_barrier();
  __builtin_amdgcn_sched_barrier(0);

  int cur = 0;
  for (int kt = 64; kt < K; kt += 32) {
    COMPUTE(cur);
    __builtin_amdgcn_s_barrier();       // all waves done reading buf[cur]
    STAGE(cur, kt);                     // refill buf[cur] with tile kt
    asm volatile("s_waitcnt vmcnt(3)" ::: "memory");  // tile in buf[cur^1] landed
    __builtin_amdgcn_s_barrier();
    __builtin_amdgcn_sched_barrier(0);  // keep next ds_reads below the barrier
    cur ^= 1;
  }
  COMPUTE(cur);
  asm volatile("s_waitcnt vmcnt(0)" ::: "memory");
  __builtin_amdgcn_s_barrier();
  __builtin_amdgcn_sched_barrier(0);
  COMPUTE(cur ^ 1);

#pragma unroll
  for (int i = 0; i < 2; ++i) {
#pragma unroll
    for (int r = 0; r < 4; ++r) {
      int row = m0 + wm + i * 16 + quad * 4 + r;
#pragma unroll
      for (int j = 0; j < 4; ++j) {
        int col = n0 + j * 16 + r16;
        size_t idx = (size_t)row * N + col;
        C[idx] = addp[idx] + acc[i][j][r];
      }
    }
  }
}

// ---------------------------------------------------------------------------
// Fused projection GEMM (R5 measured winner: 68us). Grid MUST be (41,32).
// ---------------------------------------------------------------------------
__global__ __launch_bounds__(256, 4) void gemm_proj_kernel(
    const unsigned short* __restrict__ A, const unsigned short* __restrict__ BT,
    unsigned short* __restrict__ PALL, float* __restrict__ SPRJ) {
  const int K = 1024;
  __shared__ unsigned short As[2][128][32];
  __shared__ unsigned short Bs[2][128][32];
  int flat = blockIdx.y * gridDim.x + blockIdx.x;  // 0..1311
  int xcd = flat & 7, local = flat >> 3;           // local 0..163
  int mi = local & 3, ni = local >> 2;             // mi fast (L2 B-reuse)
  int m0 = (xcd * 4 + mi) * 128;
  int n0 = ni * 128;
  int tid = threadIdx.x;
  int wave = tid >> 6, lane = tid & 63;
  int wm = (wave & 1) * 64, wn = (wave >> 1) * 64;
  int r16 = lane & 15, quad = lane >> 4;
  int lrow = lane >> 2, lcol = (lane & 3) * 8;

  f32x4 acc[4][4];
#pragma unroll
  for (int i = 0; i < 4; ++i)
#pragma unroll
    for (int j = 0; j < 4; ++j) acc[i][j] = {0.f, 0.f, 0.f, 0.f};

  // prologue: stage tile 0 into buf 0
#pragma unroll
  for (int q = 0; q < 2; ++q) {
    int rb = (wave * 2 + q) * 16;
    gld_lds16(&A[(size_t)(m0 + rb + lrow) * K + lcol], &As[0][rb][0]);
    gld_lds16(&BT[(size_t)(n0 + rb + lrow) * K + lcol], &Bs[0][rb][0]);
  }
  __syncthreads();  // drains vmcnt(0): tile 0 ready

  int cur = 0;
  for (int kt = 32; kt < K; kt += 32) {
    // prefetch next tile into the other buffer
#pragma unroll
    for (int q = 0; q < 2; ++q) {
      int rb = (wave * 2 + q) * 16;
      gld_lds16(&A[(size_t)(m0 + rb + lrow) * K + kt + lcol],
                &As[cur ^ 1][rb][0]);
      gld_lds16(&BT[(size_t)(n0 + rb + lrow) * K + kt + lcol],
                &Bs[cur ^ 1][rb][0]);
    }
    // compute current tile (prefetch latency hides under this)
    bfrag8 af[4], bq[4];
#pragma unroll
    for (int i = 0; i < 4; ++i) {
      af[i] = *(const bfrag8*)&As[cur][wm + i * 16 + r16][quad * 8];
      bq[i] = *(const bfrag8*)&Bs[cur][wn + i * 16 + r16][quad * 8];
    }
#pragma unroll
    for (int i = 0; i < 4; ++i)
#pragma unroll
      for (int j = 0; j < 4; ++j)
        acc[i][j] = __builtin_amdgcn_mfma_f32_16x16x32_bf16(af[i], bq[j],
                                                            acc[i][j], 0, 0, 0);
    __syncthreads();  // full drain: next tile staged, reads of cur done
    cur ^= 1;
  }
  // epilogue tile (no prefetch)
  {
    bfrag8 af[4], bq[4];
#pragma unroll
    for (int i = 0; i < 4; ++i) {
      af[i] = *(const bfrag8*)&As[cur][wm + i * 16 + r16][quad * 8];
      bq[i] = *(const bfrag8*)&Bs[cur][wn + i * 16 + r16][quad * 8];
    }
#pragma unroll
    for (int i = 0; i < 4; ++i)
#pragma unroll
      for (int j = 0; j < 4; ++j)
        acc[i][j] = __builtin_amdgcn_mfma_f32_16x16x32_bf16(af[i], bq[j],
                                                            acc[i][j], 0, 0, 0);
  }
  bool gates = (n0 >= 5120);  // block-uniform (ni == 40)
#pragma unroll
  for (int i = 0; i < 4; ++i) {
#pragma unroll
    for (int r = 0; r < 4; ++r) {
      int row = m0 + wm + i * 16 + quad * 4 + r;
#pragma unroll
      for (int j = 0; j < 4; ++j) {
        int col = n0 + wn + j * 16 + r16;
        if (!gates)
          PALL[(size_t)row * PSA + col] = f2bf(acc[i][j][r]);
        else
          SPRJ[(size_t)row * 128 + col - 5120] = acc[i][j][r];
      }
    }
  }
}

// ---------------------------------------------------------------------------
// Fused knorm+gates: blocks 0..16383 knorm (L2-norm k rows in PALL);
// 16384..17407 gates (sigmoid+bias+marker, head-mean).
// ---------------------------------------------------------------------------
__global__ __launch_bounds__(256) void ng_kernel(
    unsigned short* __restrict__ pall, const float* __restrict__ SPRJ,
    const float* __restrict__ bb, const float* __restrict__ bg,
    const float* __restrict__ bgt, const int* __restrict__ ids,
    float* __restrict__ beta, float* __restrict__ g, float* __restrict__ mg) {
  int f = blockIdx.x;
  if (f < 16384) {
    int w = f * 4 + (threadIdx.x >> 6);  // (b*T+t)*H + h
    int lane = threadIdx.x & 63;
    size_t addr = (size_t)(w >> 4) * PSA + (w & 15) * 64 + lane;
    float v = bf2f(pall[addr]);
    float ss = v * v;
#pragma unroll
    for (int off = 32; off; off >>= 1) ss += __shfl_xor(ss, off);
    float n = sqrtf(ss);
    n = fmaxf(n, 1e-12f);
    pall[addr] = f2bf(v / n);
  } else {
    int row = (f - 16384) * 4 + (threadIdx.x >> 6);
    int lane = threadIdx.x & 63;
    if (lane < 48) {
      int h = lane & 15;
      float v = SPRJ[(size_t)row * 128 + lane];
      float bias = (lane < 16) ? bb[h] : (lane < 32) ? bg[h] : bgt[h];
      float s = 1.f / (1.f + __expf(-(v + bias)));
      if (lane < 16) {
        float mk = (ids[row] == MARKER_ID) ? 1.f : 0.1f;
        beta[(size_t)row * 16 + h] = s * mk;
      } else if (lane < 32) {
        g[(size_t)row * 16 + h] = s;
      } else {
        float sum = s;
#pragma unroll
        for (int off = 1; off < 16; off <<= 1) sum += __shfl_xor(sum, off);
        if (lane == 32) mg[row] = sum * (1.f / 16.f);
      }
    }
  }
}

// ---------------------------------------------------------------------------
// MFMA flash sliding-window attention. Q/KL/VL at PALL cols 2048/3072/4096.
// T14 async-stage split: prefetch next K/V tile into regs BEFORE compute,
// write to LDS after the read-barrier. Q fragments hoisted out of the loop.
// ---------------------------------------------------------------------------
__global__ __launch_bounds__(256) void attn_mfma_kernel(
    const unsigned short* __restrict__ PALL, unsigned short* __restrict__ ACAT) {
  __shared__ unsigned short Qs[64][72];
  __shared__ unsigned short Ks[64][72];
  __shared__ unsigned short Vt[64][72];
  __shared__ unsigned short Ps[64][72];
  int qb = blockIdx.x * 64;
  int bh = blockIdx.y;
  int h = bh & 15, b = bh >> 4;
  int tid = threadIdx.x, lane = tid & 63, wave = tid >> 6;
  int r16 = lane & 15, quad = lane >> 4;
  int m0w = wave * 16;
  const unsigned short* Qg = PALL + (size_t)b * TT * PSA + 2048 + h * 64;
  const unsigned short* Kg = Qg + 1024;
  const unsigned short* Vg = Qg + 2048;
  int sr = tid >> 2, sq = tid & 3;
  int kt0 = qb - (int)WIN;
  if (kt0 < 0) kt0 = 0;

  // stage Q + prefetch first K/V tile into registers
  uint4 kr0, kr1;
  union { uint4 u4[2]; unsigned short s[16]; } vr;
  {
    *(uint4*)&Qs[sr][sq * 16] =
        *(const uint4*)&Qg[(size_t)(qb + sr) * PSA + sq * 16];
    *(uint4*)&Qs[sr][sq * 16 + 8] =
        *(const uint4*)&Qg[(size_t)(qb + sr) * PSA + sq * 16 + 8];
    kr0 = *(const uint4*)&Kg[(size_t)(kt0 + sr) * PSA + sq * 16];
    kr1 = *(const uint4*)&Kg[(size_t)(kt0 + sr) * PSA + sq * 16 + 8];
    vr.u4[0] = *(const uint4*)&Vg[(size_t)(kt0 + sr) * PSA + sq * 16];
    vr.u4[1] = *(const uint4*)&Vg[(size_t)(kt0 + sr) * PSA + sq * 16 + 8];
  }
  __syncthreads();  // Qs visible
  bfrag8 af0 = *(const bfrag8*)&Qs[m0w + r16][quad * 8];
  bfrag8 af1 = *(const bfrag8*)&Qs[m0w + r16][quad * 8 + 32];
  // write first K/V tile to LDS
  {
    *(uint4*)&Ks[sr][sq * 16] = kr0;
    *(uint4*)&Ks[sr][sq * 16 + 8] = kr1;
#pragma unroll
    for (int i = 0; i < 16; ++i) Vt[sq * 16 + i][sr] = vr.s[i];
  }
  __syncthreads();  // Ks/Vt visible

  float m[4], l[4];
  f32x4 o[4];
#pragma unroll
  for (int r = 0; r < 4; ++r) {
    m[r] = -1e30f;
    l[r] = 0.f;
    o[r] = {0.f, 0.f, 0.f, 0.f};
  }

  for (int kt = kt0; kt <= qb; kt += 64) {
    bool more = (kt + 64 <= qb);
    if (more) {  // prefetch next tile; latency hides under compute below
      kr0 = *(const uint4*)&Kg[(size_t)(kt + 64 + sr) * PSA + sq * 16];
      kr1 = *(const uint4*)&Kg[(size_t)(kt + 64 + sr) * PSA + sq * 16 + 8];
      vr.u4[0] = *(const uint4*)&Vg[(size_t)(kt + 64 + sr) * PSA + sq * 16];
      vr.u4[1] = *(const uint4*)&Vg[(size_t)(kt + 64 + sr) * PSA + sq * 16 + 8];
    }
    f32x4 s[4];
#pragma unroll
    for (int j = 0; j < 4; ++j) s[j] = {0.f, 0.f, 0.f, 0.f};
#pragma unroll
    for (int j = 0; j < 4; ++j) {
      bfrag8 b0 = *(const bfrag8*)&Ks[j * 16 + r16][quad * 8];
      bfrag8 b1 = *(const bfrag8*)&Ks[j * 16 + r16][quad * 8 + 32];
      s[j] = __builtin_amdgcn_mfma_f32_16x16x32_bf16(af0, b0, s[j], 0, 0, 0);
      s[j] = __builtin_amdgcn_mfma_f32_16x16x32_bf16(af1, b1, s[j], 0, 0, 0);
    }
    bool oldest = (kt == qb - (int)WIN);
    bool newest = (kt == qb);
#pragma unroll
    for (int r = 0; r < 4; ++r) {
      int il = m0w + quad * 4 + r;
      float sv[4];
#pragma unroll
      for (int j = 0; j < 4; ++j) {
        int jl = j * 16 + r16;
        float v = s[j][r] * 0.125f;
        if (oldest && jl < il) v = -1e30f;
        if (newest && jl > il) v = -1e30f;
        sv[j] = v;
      }
      float mx = fmaxf(fmaxf(sv[0], sv[1]), fmaxf(sv[2], sv[3]));
#pragma unroll
      for (int off = 1; off < 16; off <<= 1) mx = fmaxf(mx, __shfl_xor(mx, off));
      float mn = fmaxf(m[r], mx);
      float al = __expf(m[r] - mn);
      m[r] = mn;
      float rs = 0.f;
#pragma unroll
      for (int j = 0; j < 4; ++j) {
        float p = __expf(sv[j] - mn);
        rs += p;
        Ps[il][j * 16 + r16] = f2bf(p);
      }
#pragma unroll
      for (int off = 1; off < 16; off <<= 1) rs += __shfl_xor(rs, off);
      l[r] = l[r] * al + rs;
#pragma unroll
      for (int j = 0; j < 4; ++j) o[j][r] *= al;
    }
    bfrag8 pa0 = *(const bfrag8*)&Ps[m0w + r16][quad * 8];
    bfrag8 pa1 = *(const bfrag8*)&Ps[m0w + r16][quad * 8 + 32];
#pragma unroll
    for (int j = 0; j < 4; ++j) {
      bfrag8 v0 = *(const bfrag8*)&Vt[j * 16 + r16][quad * 8];
      bfrag8 v1 = *(const bfrag8*)&Vt[j * 16 + r16][quad * 8 + 32];
      o[j] = __builtin_amdgcn_mfma_f32_16x16x32_bf16(pa0, v0, o[j], 0, 0, 0);
      o[j] = __builtin_amdgcn_mfma_f32_16x16x32_bf16(pa1, v1, o[j], 0, 0, 0);
    }
    if (more) {
      __syncthreads();  // all waves done reading Ks/Vt
      *(uint4*)&Ks[sr][sq * 16] = kr0;
      *(uint4*)&Ks[sr][sq * 16 + 8] = kr1;
#pragma unroll
      for (int i = 0; i < 16; ++i) Vt[sq * 16 + i][sr] = vr.s[i];
      __syncthreads();  // next tile visible
    }
  }
#pragma unroll
  for (int r = 0; r < 4; ++r) {
    int row = m0w + quad * 4 + r;
    float inv = 1.f / l[r];
#pragma unroll
    for (int j = 0; j < 4; ++j) {
      ACAT[((size_t)(b * TT + qb + row)) * PSB + 1024 + h * 64 + j * 16 + r16] =
          f2bf(o[j][r] * inv);
    }
  }
}

// ---------------------------------------------------------------------------
// Scan phase A (per (bh,chunk)): M, u_free, Z, P, Q, a. bf16 K/V from PALL.
// ---------------------------------------------------------------------------
__global__ __launch_bounds__(256) void scan_phaseA(
    const unsigned short* __restrict__ PALL, const float* __restrict__ beta,
    const float* __restrict__ g, unsigned short* __restrict__ UFg,
    unsigned short* __restrict__ Zg, unsigned short* __restrict__ Pg,
    unsigned short* __restrict__ Qg, float* __restrict__ Ag) {
  __shared__ unsigned short Kc[64][72];
  __shared__ unsigned short KTb[64][72];
  __shared__ float Vc[64][68];
  __shared__ float Msv[64][68];
  __shared__ unsigned short UFT[64][72];
  __shared__ unsigned short ZTl[64][72];
  __shared__ float aArr[64], iaArr[64], bArr[64], baArr[64], sKT[64];
  __shared__ float aCs;

  int c = blockIdx.x, bh = blockIdx.y;
  int b = bh >> 4, h = bh & 15;
  int tc = c * 64;
  int tid = threadIdx.x, lane = tid & 63, wave = tid >> 6;
  int r16 = lane & 15, quad = lane >> 4;
  int m0w = wave * 16;
  size_t bhc = (size_t)bh * 16 + c;

  const unsigned short* kbase = PALL + ((size_t)b * TT) * PSA + h * 64;
  const unsigned short* vbase = kbase + 1024;
  const float* bbase = beta + ((size_t)b * TT) * HH + h;
  const float* gbase = g + ((size_t)b * TT) * HH + h;

  if (tid < 64) {
    int ts = tc + tid;
    bool pad = (ts > 1022);
    float gv = pad ? 1.f : gbase[(size_t)ts * HH];
    float bv = pad ? 0.f : bbase[(size_t)ts * HH];
    float p = gv;
#pragma unroll
    for (int o = 1; o < 64; o <<= 1) {
      float t = __shfl_up(p, o);
      if (lane >= o) p *= t;
    }
    aArr[tid] = p;
    iaArr[tid] = 1.f / p;
    bArr[tid] = bv;
    baArr[tid] = bv * p;
    float aC = __shfl(p, 63);
    sKT[tid] = aC / p;
    if (tid == 0) aCs = aC;
    Ag[bhc * 64 + tid] = p;
  }
  __syncthreads();
  {
    int r = tid >> 2, q = tid & 3;
    int ts = tc + r;
    float skt = sKT[r];
    union { uint4 u4[2]; unsigned short s[16]; } kv;
    kv.u4[0] = *(const uint4*)&kbase[(size_t)ts * PSA + q * 16];
    kv.u4[1] = *(const uint4*)&kbase[(size_t)ts * PSA + q * 16 + 8];
    *(uint4*)&Kc[r][q * 16] = kv.u4[0];
    *(uint4*)&Kc[r][q * 16 + 8] = kv.u4[1];
#pragma unroll
    for (int i = 0; i < 16; ++i)
      KTb[q * 16 + i][r] = f2bf(bf2f(kv.s[i]) * skt);
    if (ts <= 1022) {
      union { uint4 u4[2]; unsigned short s[16]; } vv;
      vv.u4[0] = *(const uint4*)&vbase[(size_t)(ts + 1) * PSA + q * 16];
      vv.u4[1] = *(const uint4*)&vbase[(size_t)(ts + 1) * PSA + q * 16 + 8];
#pragma unroll
      for (int i = 0; i < 16; ++i) Vc[r][q * 16 + i] = bf2f(vv.s[i]);
    } else {
#pragma unroll
      for (int i = 0; i < 16; ++i) Vc[r][q * 16 + i] = 0.f;
    }
  }
  __syncthreads();
  {
    bfrag8 af0 = *(const bfrag8*)&Kc[m0w + r16][quad * 8];
    bfrag8 af1 = *(const bfrag8*)&Kc[m0w + r16][quad * 8 + 32];
    f32x4 acc1[4];
#pragma unroll
    for (int j = 0; j < 4; ++j) acc1[j] = {0.f, 0.f, 0.f, 0.f};
#pragma unroll
    for (int j = 0; j < 4; ++j) {
      bfrag8 k0 = *(const bfrag8*)&Kc[j * 16 + r16][quad * 8];
      bfrag8 k1 = *(const bfrag8*)&Kc[j * 16 + r16][quad * 8 + 32];
      acc1[j] = __builtin_amdgcn_mfma_f32_16x16x32_bf16(af0, k0, acc1[j], 0, 0, 0);
      acc1[j] = __builtin_amdgcn_mfma_f32_16x16x32_bf16(af1, k1, acc1[j], 0, 0, 0);
    }
#pragma unroll
    for (int j = 0; j < 4; ++j) {
#pragma unroll
      for (int r = 0; r < 4; ++r) {
        int row = m0w + quad * 4 + r;
        int col = j * 16 + r16;
        Msv[row][col] =
            (col < row) ? bArr[row] * aArr[row] * iaArr[col] * acc1[j][r] : 0.f;
      }
    }
  }
  __syncthreads();
  if (wave < 2) {
    float u[64];
    if (wave == 0) {
#pragma unroll
      for (int t = 0; t < 64; ++t) u[t] = bArr[t] * Vc[t][lane];
    } else {
#pragma unroll
      for (int t = 0; t < 64; ++t) u[t] = baArr[t] * bf2f(Kc[t][lane]);
    }
#pragma unroll
    for (int t = 1; t < 64; ++t) {
      float a0 = 0.f, a1 = 0.f, a2 = 0.f, a3 = 0.f;
#pragma unroll
      for (int s4 = 0; s4 * 4 < t; ++s4) {
        float4 mr = *(const float4*)&Msv[t][s4 * 4];
        a0 = fmaf(mr.x, u[s4 * 4 + 0], a0);
        a1 = fmaf(mr.y, u[s4 * 4 + 1], a1);
        a2 = fmaf(mr.z, u[s4 * 4 + 2], a2);
        a3 = fmaf(mr.w, u[s4 * 4 + 3], a3);
      }
      u[t] -= (a0 + a1) + (a2 + a3);
    }
    unsigned short* Tls = (wave == 0) ? &UFT[lane][0] : &ZTl[lane][0];
#pragma unroll
    for (int t2 = 0; t2 < 32; ++t2) {
      unsigned int pk = (unsigned int)f2bf(u[2 * t2]) |
                        ((unsigned int)f2bf(u[2 * t2 + 1]) << 16);
      *(unsigned int*)&Tls[2 * t2] = pk;
    }
    unsigned short* Gn = (wave == 0) ? UFg : Zg;
#pragma unroll
    for (int t = 0; t < 64; ++t) {
      Gn[(bhc * 64 + t) * 64 + lane] = f2bf(u[t]);
    }
  }
  __syncthreads();
  {
    bfrag8 af0 = *(const bfrag8*)&KTb[m0w + r16][quad * 8];
    bfrag8 af1 = *(const bfrag8*)&KTb[m0w + r16][quad * 8 + 32];
    f32x4 accp[4], accq[4];
#pragma unroll
    for (int j = 0; j < 4; ++j) {
      accp[j] = {0.f, 0.f, 0.f, 0.f};
      accq[j] = {0.f, 0.f, 0.f, 0.f};
    }
#pragma unroll
    for (int j = 0; j < 4; ++j) {
      bfrag8 z0 = *(const bfrag8*)&ZTl[j * 16 + r16][quad * 8];
      bfrag8 z1 = *(const bfrag8*)&ZTl[j * 16 + r16][quad * 8 + 32];
      accp[j] = __builtin_amdgcn_mfma_f32_16x16x32_bf16(af0, z0, accp[j], 0, 0, 0);
      accp[j] = __builtin_amdgcn_mfma_f32_16x16x32_bf16(af1, z1, accp[j], 0, 0, 0);
      bfrag8 u0 = *(const bfrag8*)&UFT[j * 16 + r16][quad * 8];
      bfrag8 u1 = *(const bfrag8*)&UFT[j * 16 + r16][quad * 8 + 32];
      accq[j] = __builtin_amdgcn_mfma_f32_16x16x32_bf16(af0, u0, accq[j], 0, 0, 0);
      accq[j] = __builtin_amdgcn_mfma_f32_16x16x32_bf16(af1, u1, accq[j], 0, 0, 0);
    }
    float aC = aCs;
#pragma unroll
    for (int j = 0; j < 4; ++j) {
#pragma unroll
      for (int r = 0; r < 4; ++r) {
        int row = m0w + quad * 4 + r;
        int col = j * 16 + r16;
        float pv = ((row == col) ? aC : 0.f) - accp[j][r];
        Pg[bhc * 4096 + (size_t)row * 64 + col] = f2bf(pv);
        Qg[bhc * 4096 + (size_t)row * 64 + col] = f2bf(accq[j][r]);
      }
    }
  }
}

// ---------------------------------------------------------------------------
// Scan phase B: serial S_{c+1} = P_c S_c + Q_c.
// ---------------------------------------------------------------------------
__global__ __launch_bounds__(256) void scan_phaseB(
    const float* __restrict__ S0, const unsigned short* __restrict__ Pg,
    const unsigned short* __restrict__ Qg, unsigned short* __restrict__ SinTg,
    float* __restrict__ Sf, unsigned short* __restrict__ ACAT) {
  __shared__ unsigned short STb[64][72];
  __shared__ unsigned short Pl[64][72];
  int bh = blockIdx.x;
  int b = bh >> 4, h = bh & 15;
  int tid = threadIdx.x, lane = tid & 63, wave = tid >> 6;
  int r16 = lane & 15, quad = lane >> 4;
  int m0w = wave * 16;
  int rr = tid >> 2, qq = tid & 3;
  {
    const float* s0p = S0 + (size_t)bh * 4096;
#pragma unroll
    for (int i = 0; i < 4; ++i) {
      float4 sv = *(const float4*)&s0p[rr * 64 + qq * 16 + i * 4];
      STb[qq * 16 + i * 4 + 0][rr] = f2bf(sv.x);
      STb[qq * 16 + i * 4 + 1][rr] = f2bf(sv.y);
      STb[qq * 16 + i * 4 + 2][rr] = f2bf(sv.z);
      STb[qq * 16 + i * 4 + 3][rr] = f2bf(sv.w);
    }
    if (tid < 64) ACAT[((size_t)b * TT) * PSB + h * 64 + tid] = 0;
  }
  for (int c = 0; c < 16; ++c) {
    size_t bhc = (size_t)bh * 16 + c;
    __syncthreads();
    {
      uint4 s0v = *(const uint4*)&STb[rr][qq * 16];
      uint4 s1v = *(const uint4*)&STb[rr][qq * 16 + 8];
      *(uint4*)&SinTg[bhc * 4096 + (size_t)rr * 64 + qq * 16] = s0v;
      *(uint4*)&SinTg[bhc * 4096 + (size_t)rr * 64 + qq * 16 + 8] = s1v;
      uint4 p0 = *(const uint4*)&Pg[bhc * 4096 + (size_t)rr * 64 + qq * 16];
      uint4 p1 = *(const uint4*)&Pg[bhc * 4096 + (size_t)rr * 64 + qq * 16 + 8];
      *(uint4*)&Pl[rr][qq * 16] = p0;
      *(uint4*)&Pl[rr][qq * 16 + 8] = p1;
    }
    __syncthreads();
    f32x4 acc[4];
#pragma unroll
    for (int j = 0; j < 4; ++j) acc[j] = {0.f, 0.f, 0.f, 0.f};
    {
      bfrag8 af0 = *(const bfrag8*)&Pl[m0w + r16][quad * 8];
      bfrag8 af1 = *(const bfrag8*)&Pl[m0w + r16][quad * 8 + 32];
#pragma unroll
      for (int j = 0; j < 4; ++j) {
        bfrag8 s0v = *(const bfrag8*)&STb[j * 16 + r16][quad * 8];
        bfrag8 s1v = *(const bfrag8*)&STb[j * 16 + r16][quad * 8 + 32];
        acc[j] = __builtin_amdgcn_mfma_f32_16x16x32_bf16(af0, s0v, acc[j], 0, 0, 0);
        acc[j] = __builtin_amdgcn_mfma_f32_16x16x32_bf16(af1, s1v, acc[j], 0, 0, 0);
      }
    }
    float snew[4][4];
#pragma unroll
    for (int j = 0; j < 4; ++j) {
#pragma unroll
      for (int r = 0; r < 4; ++r) {
        int row = m0w + quad * 4 + r;
        int col = j * 16 + r16;
        snew[j][r] = acc[j][r] + bf2f(Qg[bhc * 4096 + (size_t)row * 64 + col]);
      }
    }
    __syncthreads();
#pragma unroll
    for (int j = 0; j < 4; ++j) {
#pragma unroll
      for (int r = 0; r < 4; ++r) {
        int row = m0w + quad * 4 + r;
        int col = j * 16 + r16;
        STb[col][row] = f2bf(snew[j][r]);
        if (c == 15) Sf[(size_t)bh * 4096 + (size_t)row * 64 + col] = snew[j][r];
      }
    }
  }
}

// ---------------------------------------------------------------------------
// Scan phase C v2: O = diag(a) K S_in + W U -> ACAT col 0.
// LDS 36.5KB (Z/U direct from global); launch_bounds(256,4).
// ---------------------------------------------------------------------------
__global__ __launch_bounds__(256, 4) void scan_phaseC(
    const unsigned short* __restrict__ PALL,
    const unsigned short* __restrict__ UFg,
    const unsigned short* __restrict__ Zg,
    const unsigned short* __restrict__ SinTg, const float* __restrict__ Ag,
    unsigned short* __restrict__ ACAT) {
  __shared__ unsigned short Kc[64][72];
  __shared__ unsigned short SvT[64][72];
  __shared__ unsigned short Wl[64][72];
  __shared__ unsigned short UTl[64][72];
  __shared__ float aA[64], iaA[64];

  int c = blockIdx.x, bh = blockIdx.y;
  int b = bh >> 4, h = bh & 15;
  int tc = c * 64;
  int tid = threadIdx.x, lane = tid & 63, wave = tid >> 6;
  int r16 = lane & 15, quad = lane >> 4;
  int m0w = wave * 16;
  size_t bhc = (size_t)bh * 16 + c;
  const unsigned short* kbase = PALL + ((size_t)b * TT) * PSA + h * 64;

  if (tid < 64) {
    float av = Ag[bhc * 64 + tid];
    aA[tid] = av;
    iaA[tid] = 1.f / av;
  }
  {
    int r = tid >> 2, q = tid & 3;
    int ts = tc + r;
    *(uint4*)&Kc[r][q * 16] = *(const uint4*)&kbase[(size_t)ts * PSA + q * 16];
    *(uint4*)&Kc[r][q * 16 + 8] =
        *(const uint4*)&kbase[(size_t)ts * PSA + q * 16 + 8];
    uint4 sv0 = *(const uint4*)&SinTg[bhc * 4096 + (size_t)r * 64 + q * 16];
    uint4 sv1 = *(const uint4*)&SinTg[bhc * 4096 + (size_t)r * 64 + q * 16 + 8];
    *(uint4*)&SvT[r][q * 16] = sv0;
    *(uint4*)&SvT[r][q * 16 + 8] = sv1;
  }
  // Z fragments direct from global (A-operand layout: row m0w+r16)
  bfrag8 zf0 =
      *(const bfrag8*)&Zg[(bhc * 64 + m0w + r16) * 64 + quad * 8];
  bfrag8 zf1 =
      *(const bfrag8*)&Zg[(bhc * 64 + m0w + r16) * 64 + quad * 8 + 32];
  __syncthreads();
  float op[4][4];
  {
    bfrag8 af0 = *(const bfrag8*)&Kc[m0w + r16][quad * 8];
    bfrag8 af1 = *(const bfrag8*)&Kc[m0w + r16][quad * 8 + 32];
    f32x4 acc1[4], acc2[4], acc3[4];
#pragma unroll
    for (int j = 0; j < 4; ++j) {
      acc1[j] = {0.f, 0.f, 0.f, 0.f};
      acc2[j] = {0.f, 0.f, 0.f, 0.f};
      acc3[j] = {0.f, 0.f, 0.f, 0.f};
    }
#pragma unroll
    for (int j = 0; j < 4; ++j) {
      bfrag8 k0 = *(const bfrag8*)&Kc[j * 16 + r16][quad * 8];
      bfrag8 k1 = *(const bfrag8*)&Kc[j * 16 + r16][quad * 8 + 32];
      acc1[j] = __builtin_amdgcn_mfma_f32_16x16x32_bf16(af0, k0, acc1[j], 0, 0, 0);
      acc1[j] = __builtin_amdgcn_mfma_f32_16x16x32_bf16(af1, k1, acc1[j], 0, 0, 0);
      bfrag8 s0 = *(const bfrag8*)&SvT[j * 16 + r16][quad * 8];
      bfrag8 s1 = *(const bfrag8*)&SvT[j * 16 + r16][quad * 8 + 32];
      acc3[j] = __builtin_amdgcn_mfma_f32_16x16x32_bf16(af0, s0, acc3[j], 0, 0, 0);
      acc3[j] = __builtin_amdgcn_mfma_f32_16x16x32_bf16(af1, s1, acc3[j], 0, 0, 0);
      acc2[j] = __builtin_amdgcn_mfma_f32_16x16x32_bf16(zf0, s0, acc2[j], 0, 0, 0);
      acc2[j] = __builtin_amdgcn_mfma_f32_16x16x32_bf16(zf1, s1, acc2[j], 0, 0, 0);
    }
#pragma unroll
    for (int j = 0; j < 4; ++j) {
#pragma unroll
      for (int r = 0; r < 4; ++r) {
        int row = m0w + quad * 4 + r;
        int col = j * 16 + r16;
        Wl[row][col] = (col <= row) ? f2bf(aA[row] * iaA[col] * acc1[j][r])
                                    : (unsigned short)0;
        // U elementwise direct from global (each thread its own (row,col))
        float uval =
            bf2f(UFg[(bhc * 64 + row) * 64 + col]) - acc2[j][r];
        UTl[col][row] = f2bf(uval);
        op[j][r] = aA[row] * acc3[j][r];
      }
    }
  }
  __syncthreads();
  {
    bfrag8 wf0 = *(const bfrag8*)&Wl[m0w + r16][quad * 8];
    bfrag8 wf1 = *(const bfrag8*)&Wl[m0w + r16][quad * 8 + 32];
    f32x4 acc4[4];
#pragma unroll
    for (int j = 0; j < 4; ++j) acc4[j] = {0.f, 0.f, 0.f, 0.f};
#pragma unroll
    for (int j = 0; j < 4; ++j) {
      bfrag8 u0 = *(const bfrag8*)&UTl[j * 16 + r16][quad * 8];
      bfrag8 u1 = *(const bfrag8*)&UTl[j * 16 + r16][quad * 8 + 32];
      acc4[j] = __builtin_amdgcn_mfma_f32_16x16x32_bf16(wf0, u0, acc4[j], 0, 0, 0);
      acc4[j] = __builtin_amdgcn_mfma_f32_16x16x32_bf16(wf1, u1, acc4[j], 0, 0, 0);
    }
#pragma unroll
    for (int j = 0; j < 4; ++j) {
#pragma unroll
      for (int r = 0; r < 4; ++r) {
        int row = m0w + quad * 4 + r;
        int col = j * 16 + r16;
        int ts = tc + row;
        if (ts < 1023) {
          ACAT[((size_t)b * TT + ts + 1) * PSB + h * 64 + col] =
              f2bf(op[j][r] + acc4[j][r]);
        }
      }
    }
  }
}

// ---------------------------------------------------------------------------
// retrieved = (k_shared @ Sf) * mg -> ACAT col 2048 (bf16). LDS-staged Sf
// (R6 form). Grid (16 t-chunks, 64 bh).
// ---------------------------------------------------------------------------
__global__ __launch_bounds__(256) void retrieve_kernel(
    const unsigned short* __restrict__ PALL, const float* __restrict__ Sf,
    const float* __restrict__ mg, unsigned short* __restrict__ ACAT) {
  __shared__ float Sfs[64][64];  // [k][v]; row-broadcast reads: conflict-free
  int tc = blockIdx.x * 64;
  int bh = blockIdx.y;
  int b = bh >> 4, h = bh & 15;
  int tid = threadIdx.x, lane = tid & 63, wave = tid >> 6;
  const float* sfp = Sf + (size_t)bh * 4096;
#pragma unroll
  for (int i = 0; i < 4; ++i) {
    int e = tid + i * 256;  // float4 index 0..1023
    ((float4*)&Sfs[0][0])[e] = ((const float4*)sfp)[e];
  }
  __syncthreads();
  const unsigned short* kb = PALL + ((size_t)b * TT) * PSA + h * 64;
#pragma unroll 2
  for (int ti = 0; ti < 16; ++ti) {
    int t = tc + wave * 16 + ti;
    size_t bt = (size_t)b * TT + t;
    float kl = bf2f(kb[(size_t)t * PSA + lane]);  // lane = k (coalesced)
    float a0 = 0.f, a1 = 0.f, a2 = 0.f, a3 = 0.f;
#pragma unroll
    for (int k = 0; k < 64; k += 4) {
      a0 = fmaf(__shfl(kl, k + 0), Sfs[k + 0][lane], a0);
      a1 = fmaf(__shfl(kl, k + 1), Sfs[k + 1][lane], a1);
      a2 = fmaf(__shfl(kl, k + 2), Sfs[k + 2][lane], a2);
      a3 = fmaf(__shfl(kl, k + 3), Sfs[k + 3][lane], a3);
    }
    float acc = (a0 + a1) + (a2 + a3);
    ACAT[bt * PSB + 2048 + h * 64 + lane] = f2bf(acc * mg[bt]);
  }
}

// ---------------------------------------------------------------------------
extern "C" void kernel_launch(void* const* d_in, const int* in_sizes, int n_in,
                              void* d_out, int out_size, void* d_ws,
                              size_t ws_size, hipStream_t stream) {
  (void)in_sizes; (void)n_in; (void)out_size; (void)ws_size;
  const float* x       = (const float*)d_in[0];
  const float* S0      = (const float*)d_in[1];
  const float* W_k     = (const float*)d_in[2];
  const float* W_v     = (const float*)d_in[3];
  const float* W_gdn_o = (const float*)d_in[4];
  const float* W_beta  = (const float*)d_in[5];
  const float* b_beta  = (const float*)d_in[6];
  const float* W_g     = (const float*)d_in[7];
  const float* b_g     = (const float*)d_in[8];
  const float* W_lq    = (const float*)d_in[9];
  const float* W_lk    = (const float*)d_in[10];
  const float* W_lv    = (const float*)d_in[11];
  const float* W_swa_o = (const float*)d_in[12];
  const float* W_ret_o = (const float*)d_in[13];
  const float* W_gate  = (const float*)d_in[14];
  const float* b_gate  = (const float*)d_in[15];
  const float* norm_w  = (const float*)d_in[16];
  const int*   ids     = (const int*)d_in[17];
  float* out = (float*)d_out;

  char* ws = (char*)d_ws;
  size_t off = 0;
  auto allocf = [&](size_t n) {
    float* p = (float*)(ws + off);
    off += n * sizeof(float);
    return p;
  };
  auto allocu = [&](size_t n) {
    unsigned short* p = (unsigned short*)(ws + off);
    off += n * sizeof(unsigned short);
    return p;
  };
  const int M = BB * TT;  // 4096
  unsigned short* XNb    = allocu((size_t)M * DD);
  unsigned short* PALL   = allocu((size_t)M * PSA);   // K|V|Q|KL|VL bf16
  unsigned short* ACAT   = allocu((size_t)M * PSB);   // gdn | local | retr
  float*          SPRJ   = allocf((size_t)M * 128);   // gate logits
  unsigned short* WTcat5 = allocu((size_t)NPROJ * 1024);
  unsigned short* WTcat3 = allocu((size_t)1024 * PSB);
  float* BETA = allocf((size_t)M * HH);
  float* Gg   = allocf((size_t)M * HH);
  float* MG   = allocf((size_t)M);
  float* SF   = allocf((size_t)BB * HH * KK * VV);
  const size_t CH = (size_t)BB * HH * 16 * 64 * 64;
  unsigned short* UFg   = allocu(CH);
  unsigned short* Zg    = allocu(CH);
  unsigned short* Pg    = allocu(CH);
  unsigned short* Qg    = allocu(CH);
  unsigned short* SinTg = allocu(CH);
  float* Ag = allocf((size_t)BB * HH * 16 * 64);

  // rmsnorm (4096 blocks) + convert_wt (2304 blocks) fused
  prep_kernel<<<6400, 256, 0, stream>>>(x, norm_w, XNb, W_k, W_v, W_lq, W_lk,
                                        W_lv, W_gdn_o, W_swa_o, W_ret_o,
                                        W_beta, W_g, W_gate, WTcat5, WTcat3);

  gemm_proj_kernel<<<dim3(41, 32), 256, 0, stream>>>(XNb, WTcat5, PALL, SPRJ);

  // knorm (16384 blocks) + gates (1024 blocks) fused
  ng_kernel<<<17408, 256, 0, stream>>>(PALL, SPRJ, b_beta, b_g, b_gate, ids,
                                       BETA, Gg, MG);

  scan_phaseA<<<dim3(16, BB * HH), 256, 0, stream>>>(PALL, BETA, Gg, UFg, Zg,
                                                     Pg, Qg, Ag);
  scan_phaseB<<<BB * HH, 256, 0, stream>>>(S0, Pg, Qg, SinTg, SF, ACAT);
  scan_phaseC<<<dim3(16, BB * HH), 256, 0, stream>>>(PALL, UFg, Zg, SinTg, Ag,
                                                     ACAT);

  attn_mfma_kernel<<<dim3(TT / 64, BB * HH), 256, 0, stream>>>(PALL, ACAT);

  retrieve_kernel<<<dim3(TT / 64, BB * HH), 256, 0, stream>>>(PALL, SF, MG,
                                                              ACAT);

  // out = x + [gdn | local*0.3W | retr*mg] @ WTcat3^T  (K=3072, 512 blocks)
  gemm_out_kernel<<<dim3(16, 32), 256, 0, stream>>>(ACAT, WTcat3, out, x, M, DD,
                                                    3072);
}

// Round 12
// 369.049 us; speedup vs baseline: 1.2571x; 1.0252x over previous
//
#include <hip/hip_runtime.h>
#include <hip/hip_bf16.h>

// Problem constants
#define BB 4
#define TT 1024
#define DD 1024
#define HH 16
#define KK 64
#define VV 64
#define WIN 256
#define MARKER_ID 50251
#define PSA 5120   // bf16 all-proj row stride: K|V|Q|KL|VL
#define PSB 3072   // epilogue-cat row stride (gdn|local|retr)
#define NPROJ 5248 // proj GEMM N: 5120 bf16 + 128 gates(48+80 pad)

typedef short bfrag8 __attribute__((ext_vector_type(8)));
typedef float f32x4 __attribute__((ext_vector_type(4)));

static __device__ __forceinline__ unsigned short f2bf(float f) {
  __hip_bfloat16 h = __float2bfloat16(f);
  union { __hip_bfloat16 h; unsigned short u; } cv;
  cv.h = h;
  return cv.u;
}
static __device__ __forceinline__ float bf2f(unsigned short u) {
  union { unsigned int i; float f; } c;
  c.i = ((unsigned int)u) << 16;
  return c.f;
}
// Async global->LDS, 16B per lane. LDS dest = wave-uniform base + lane*16.
static __device__ __forceinline__ void gld_lds16(const unsigned short* g,
                                                 unsigned short* l) {
  __builtin_amdgcn_global_load_lds(
      (const __attribute__((address_space(1))) void*)g,
      (__attribute__((address_space(3))) void*)l, 16, 0, 0);
}

// ---------------------------------------------------------------------------
// RMSNorm body: xnb (bf16) = x / sqrt(mean(x^2)+eps) * norm_w. One block/row.
// ---------------------------------------------------------------------------
static __device__ __forceinline__ void rmsnorm_body(
    int row, const float* __restrict__ x, const float* __restrict__ nw,
    unsigned short* __restrict__ xnb, float* red) {
  int tid = threadIdx.x;
  const float4* xr = (const float4*)(x + (size_t)row * DD);
  float4 v = xr[tid];
  float ss = v.x * v.x + v.y * v.y + v.z * v.z + v.w * v.w;
#pragma unroll
  for (int off = 32; off; off >>= 1) ss += __shfl_xor(ss, off);
  int wid = tid >> 6;
  if ((tid & 63) == 0) red[wid] = ss;
  __syncthreads();
  float tot = red[0] + red[1] + red[2] + red[3];
  float inv = 1.0f / sqrtf(tot * (1.0f / DD) + 1e-6f);
  const float4* wr = (const float4*)nw;
  float4 wv = wr[tid];
  ushort4 o;
  o.x = f2bf(v.x * inv * wv.x);
  o.y = f2bf(v.y * inv * wv.y);
  o.z = f2bf(v.z * inv * wv.z);
  o.w = f2bf(v.w * inv * wv.w);
  *(ushort4*)&xnb[(size_t)row * DD + tid * 4] = o;
}

// ---------------------------------------------------------------------------
// Convert weights body: fp32 [K][N] -> bf16 [N][K] concatenated buffers.
// z=0..7: 1024x1024 weights. z=8: gate weights + zero-pad.
// ---------------------------------------------------------------------------
static __device__ __forceinline__ void convert_body(
    int xb, int yb, int zb, const float* W0, const float* W1, const float* W2,
    const float* W3, const float* W4, const float* W5, const float* W6,
    const float* W7, const float* Wb, const float* Wg, const float* Wgt,
    unsigned short* C5, unsigned short* C3, float (*Ts)[68]) {
  int tid = threadIdx.x;
  if (zb == 8) {
    if (xb != 0) return;
    int k0 = yb * 64;
    for (int e = tid; e < 3 * 16 * 64; e += 256) {
      int w = e >> 10;
      int h = (e >> 6) & 15;
      int kk = e & 63;
      const float* Ws = (w == 0) ? Wb : (w == 1) ? Wg : Wgt;
      C5[(size_t)(5120 + w * 16 + h) * 1024 + k0 + kk] =
          f2bf(Ws[(size_t)(k0 + kk) * 16 + h]);
    }
    for (int e = tid; e < 80 * 64; e += 256) {
      int r = e >> 6, kk = e & 63;
      C5[(size_t)(5168 + r) * 1024 + k0 + kk] = 0;
    }
    return;
  }
  const float* W;
  unsigned short* T;
  int stride;
  float scale = 1.f;
  switch (zb) {
    case 0: W = W0; T = C5 + 0 * 1024 * 1024; stride = 1024; break;
    case 1: W = W1; T = C5 + 1 * 1024 * 1024; stride = 1024; break;
    case 2: W = W2; T = C5 + 2 * 1024 * 1024; stride = 1024; break;
    case 3: W = W3; T = C5 + 3 * 1024 * 1024; stride = 1024; break;
    case 4: W = W4; T = C5 + 4 * 1024 * 1024; stride = 1024; break;
    case 5: W = W5; T = C3 + 0; stride = PSB; break;
    case 6: W = W6; T = C3 + 1024; stride = PSB; scale = 0.3f; break;
    default: W = W7; T = C3 + 2048; stride = PSB; break;
  }
  int n0 = xb * 64, k0 = yb * 64;
#pragma unroll
  for (int p = 0; p < 4; ++p) {
    int e = p * 256 + tid;
    int k = e >> 4, nq = e & 15;
    float4 w = *(const float4*)&W[(size_t)(k0 + k) * 1024 + n0 + nq * 4];
    Ts[nq * 4 + 0][k] = w.x;
    Ts[nq * 4 + 1][k] = w.y;
    Ts[nq * 4 + 2][k] = w.z;
    Ts[nq * 4 + 3][k] = w.w;
  }
  __syncthreads();
#pragma unroll
  for (int p = 0; p < 4; ++p) {
    int e = p * 256 + tid;
    int n = e >> 4, kq = e & 15;
    float4 v = *(const float4*)&Ts[n][kq * 4];
    ushort4 u;
    u.x = f2bf(v.x * scale);
    u.y = f2bf(v.y * scale);
    u.z = f2bf(v.z * scale);
    u.w = f2bf(v.w * scale);
    *(ushort4*)&T[(size_t)(n0 + n) * stride + k0 + kq * 4] = u;
  }
}

// ---------------------------------------------------------------------------
// Fused prep: blocks 0..4095 rmsnorm; 4096..6399 convert_wt (decode x,y,z).
// ---------------------------------------------------------------------------
__global__ __launch_bounds__(256) void prep_kernel(
    const float* __restrict__ x, const float* __restrict__ nw,
    unsigned short* __restrict__ xnb, const float* W0, const float* W1,
    const float* W2, const float* W3, const float* W4, const float* W5,
    const float* W6, const float* W7, const float* Wb, const float* Wg,
    const float* Wgt, unsigned short* C5, unsigned short* C3) {
  __shared__ __align__(16) float Ts[64][68];
  int f = blockIdx.x;
  if (f < 4096) {
    rmsnorm_body(f, x, nw, xnb, &Ts[0][0]);
  } else {
    int c = f - 4096;  // 0..2303 = 9 z * 16 y * 16 x
    convert_body(c & 15, (c >> 4) & 15, c >> 8, W0, W1, W2, W3, W4, W5, W6, W7,
                 Wb, Wg, Wgt, C5, C3, Ts);
  }
}

// ---------------------------------------------------------------------------
// Epilogue GEMM: out = x + ACAT[4096][3072] @ WTcat3[1024][3072]^T.
// 128M x 64N tile -> 512 blocks. XCD swizzle. Grid MUST be (16, 32).
// Counted-vmcnt 2-deep pipeline (R2 winner) + launch_bounds(256,4)
// (R11 measured winner: total -7us).
// ---------------------------------------------------------------------------
__global__ __launch_bounds__(256, 4) void gemm_out_kernel(
    const unsigned short* __restrict__ A, const unsigned short* __restrict__ BT,
    float* __restrict__ C, const float* __restrict__ addp, int M, int N,
    int K) {
  __shared__ unsigned short As[2][128][32];
  __shared__ unsigned short Bs[2][64][32];
  int flat = blockIdx.y * gridDim.x + blockIdx.x;
  int xcd = flat & 7, local = flat >> 3;
  int m0 = (xcd * 4 + (local & 3)) * 128;
  int n0 = (local >> 2) * 64;
  int tid = threadIdx.x;
  int wave = tid >> 6, lane = tid & 63;
  int wm = wave * 32;
  int r16 = lane & 15, quad = lane >> 4;
  int lrow = lane >> 2, lcol = (lane & 3) * 8;

  f32x4 acc[2][4];
#pragma unroll
  for (int i = 0; i < 2; ++i)
#pragma unroll
    for (int j = 0; j < 4; ++j) acc[i][j] = {0.f, 0.f, 0.f, 0.f};

  auto STAGE = [&](int buf, int kt) {
#pragma unroll
    for (int q = 0; q < 2; ++q) {
      int rb = (wave * 2 + q) * 16;
      gld_lds16(&A[(size_t)(m0 + rb + lrow) * K + kt + lcol], &As[buf][rb][0]);
    }
    {
      int rb = wave * 16;
      gld_lds16(&BT[(size_t)(n0 + rb + lrow) * K + kt + lcol], &Bs[buf][rb][0]);
    }
  };
  auto COMPUTE = [&](int buf) {
    bfrag8 af[2], bq[4];
#pragma unroll
    for (int i = 0; i < 2; ++i)
      af[i] = *(const bfrag8*)&As[buf][wm + i * 16 + r16][quad * 8];
#pragma unroll
    for (int j = 0; j < 4; ++j)
      bq[j] = *(const bfrag8*)&Bs[buf][j * 16 + r16][quad * 8];
#pragma unroll
    for (int i = 0; i < 2; ++i)
#pragma unroll
      for (int j = 0; j < 4; ++j)
        acc[i][j] = __builtin_amdgcn_mfma_f32_16x16x32_bf16(af[i], bq[j],
                                                            acc[i][j], 0, 0, 0);
  };

  // prologue: 2 tiles in flight (3 loads/wave each)
  STAGE(0, 0);
  STAGE(1, 32);
  asm volatile("s_waitcnt vmcnt(3)" ::: "memory");  // tile 0 landed
  __builtin_amdgcn_s_barrier();
  __builtin_amdgcn_sched_barrier(0);

  int cur = 0;
  for (int kt = 64; kt < K; kt += 32) {
    COMPUTE(cur);
    __builtin_amdgcn_s_barrier();       // all waves done reading buf[cur]
    STAGE(cur, kt);                     // refill buf[cur] with tile kt
    asm volatile("s_waitcnt vmcnt(3)" ::: "memory");  // tile in buf[cur^1] landed
    __builtin_amdgcn_s_barrier();
    __builtin_amdgcn_sched_barrier(0);  // keep next ds_reads below the barrier
    cur ^= 1;
  }
  COMPUTE(cur);
  asm volatile("s_waitcnt vmcnt(0)" ::: "memory");
  __builtin_amdgcn_s_barrier();
  __builtin_amdgcn_sched_barrier(0);
  COMPUTE(cur ^ 1);

#pragma unroll
  for (int i = 0; i < 2; ++i) {
#pragma unroll
    for (int r = 0; r < 4; ++r) {
      int row = m0 + wm + i * 16 + quad * 4 + r;
#pragma unroll
      for (int j = 0; j < 4; ++j) {
        int col = n0 + j * 16 + r16;
        size_t idx = (size_t)row * N + col;
        C[idx] = addp[idx] + acc[i][j][r];
      }
    }
  }
}

// ---------------------------------------------------------------------------
// Fused projection GEMM (R5 measured winner: 68us). Grid MUST be (41,32).
// ---------------------------------------------------------------------------
__global__ __launch_bounds__(256, 4) void gemm_proj_kernel(
    const unsigned short* __restrict__ A, const unsigned short* __restrict__ BT,
    unsigned short* __restrict__ PALL, float* __restrict__ SPRJ) {
  const int K = 1024;
  __shared__ unsigned short As[2][128][32];
  __shared__ unsigned short Bs[2][128][32];
  int flat = blockIdx.y * gridDim.x + blockIdx.x;  // 0..1311
  int xcd = flat & 7, local = flat >> 3;           // local 0..163
  int mi = local & 3, ni = local >> 2;             // mi fast (L2 B-reuse)
  int m0 = (xcd * 4 + mi) * 128;
  int n0 = ni * 128;
  int tid = threadIdx.x;
  int wave = tid >> 6, lane = tid & 63;
  int wm = (wave & 1) * 64, wn = (wave >> 1) * 64;
  int r16 = lane & 15, quad = lane >> 4;
  int lrow = lane >> 2, lcol = (lane & 3) * 8;

  f32x4 acc[4][4];
#pragma unroll
  for (int i = 0; i < 4; ++i)
#pragma unroll
    for (int j = 0; j < 4; ++j) acc[i][j] = {0.f, 0.f, 0.f, 0.f};

  // prologue: stage tile 0 into buf 0
#pragma unroll
  for (int q = 0; q < 2; ++q) {
    int rb = (wave * 2 + q) * 16;
    gld_lds16(&A[(size_t)(m0 + rb + lrow) * K + lcol], &As[0][rb][0]);
    gld_lds16(&BT[(size_t)(n0 + rb + lrow) * K + lcol], &Bs[0][rb][0]);
  }
  __syncthreads();  // drains vmcnt(0): tile 0 ready

  int cur = 0;
  for (int kt = 32; kt < K; kt += 32) {
    // prefetch next tile into the other buffer
#pragma unroll
    for (int q = 0; q < 2; ++q) {
      int rb = (wave * 2 + q) * 16;
      gld_lds16(&A[(size_t)(m0 + rb + lrow) * K + kt + lcol],
                &As[cur ^ 1][rb][0]);
      gld_lds16(&BT[(size_t)(n0 + rb + lrow) * K + kt + lcol],
                &Bs[cur ^ 1][rb][0]);
    }
    // compute current tile (prefetch latency hides under this)
    bfrag8 af[4], bq[4];
#pragma unroll
    for (int i = 0; i < 4; ++i) {
      af[i] = *(const bfrag8*)&As[cur][wm + i * 16 + r16][quad * 8];
      bq[i] = *(const bfrag8*)&Bs[cur][wn + i * 16 + r16][quad * 8];
    }
#pragma unroll
    for (int i = 0; i < 4; ++i)
#pragma unroll
      for (int j = 0; j < 4; ++j)
        acc[i][j] = __builtin_amdgcn_mfma_f32_16x16x32_bf16(af[i], bq[j],
                                                            acc[i][j], 0, 0, 0);
    __syncthreads();  // full drain: next tile staged, reads of cur done
    cur ^= 1;
  }
  // epilogue tile (no prefetch)
  {
    bfrag8 af[4], bq[4];
#pragma unroll
    for (int i = 0; i < 4; ++i) {
      af[i] = *(const bfrag8*)&As[cur][wm + i * 16 + r16][quad * 8];
      bq[i] = *(const bfrag8*)&Bs[cur][wn + i * 16 + r16][quad * 8];
    }
#pragma unroll
    for (int i = 0; i < 4; ++i)
#pragma unroll
      for (int j = 0; j < 4; ++j)
        acc[i][j] = __builtin_amdgcn_mfma_f32_16x16x32_bf16(af[i], bq[j],
                                                            acc[i][j], 0, 0, 0);
  }
  bool gates = (n0 >= 5120);  // block-uniform (ni == 40)
#pragma unroll
  for (int i = 0; i < 4; ++i) {
#pragma unroll
    for (int r = 0; r < 4; ++r) {
      int row = m0 + wm + i * 16 + quad * 4 + r;
#pragma unroll
      for (int j = 0; j < 4; ++j) {
        int col = n0 + wn + j * 16 + r16;
        if (!gates)
          PALL[(size_t)row * PSA + col] = f2bf(acc[i][j][r]);
        else
          SPRJ[(size_t)row * 128 + col - 5120] = acc[i][j][r];
      }
    }
  }
}

// ---------------------------------------------------------------------------
// Fused knorm+gates v2. knorm: ONE BLOCK PER bt ROW (4096 blocks) — reads
// the full 2KB k-region contiguously (ushort4/lane), 16-lane group = one
// head, shfl_xor 1/2/4/8 for the norm. Replaces the old 128B-per-wave
// scattered pattern (2 cache lines/wave -> latency-bound at 1.4TB/s).
// Blocks 4096..5119: gates (unchanged).
// ---------------------------------------------------------------------------
__global__ __launch_bounds__(256) void ng_kernel(
    unsigned short* __restrict__ pall, const float* __restrict__ SPRJ,
    const float* __restrict__ bb, const float* __restrict__ bg,
    const float* __restrict__ bgt, const int* __restrict__ ids,
    float* __restrict__ beta, float* __restrict__ g, float* __restrict__ mg) {
  int f = blockIdx.x;
  int tid = threadIdx.x;
  if (f < 4096) {
    // knorm: row f of PALL, cols 0..1023 (k_shared, 16 heads x 64)
    size_t base = (size_t)f * PSA;
    ushort4 v4 = *(const ushort4*)&pall[base + tid * 4];
    float v0 = bf2f(v4.x), v1 = bf2f(v4.y), v2 = bf2f(v4.z), v3 = bf2f(v4.w);
    float ss = v0 * v0 + v1 * v1 + v2 * v2 + v3 * v3;
    // head = tid>>4; 16-lane groups are wave-aligned -> shfl_xor stays in-head
#pragma unroll
    for (int off = 1; off < 16; off <<= 1) ss += __shfl_xor(ss, off);
    float inv = 1.0f / fmaxf(sqrtf(ss), 1e-12f);
    ushort4 o;
    o.x = f2bf(v0 * inv);
    o.y = f2bf(v1 * inv);
    o.z = f2bf(v2 * inv);
    o.w = f2bf(v3 * inv);
    *(ushort4*)&pall[base + tid * 4] = o;
  } else {
    int row = (f - 4096) * 4 + (tid >> 6);
    int lane = tid & 63;
    if (lane < 48) {
      int h = lane & 15;
      float v = SPRJ[(size_t)row * 128 + lane];
      float bias = (lane < 16) ? bb[h] : (lane < 32) ? bg[h] : bgt[h];
      float s = 1.f / (1.f + __expf(-(v + bias)));
      if (lane < 16) {
        float mk = (ids[row] == MARKER_ID) ? 1.f : 0.1f;
        beta[(size_t)row * 16 + h] = s * mk;
      } else if (lane < 32) {
        g[(size_t)row * 16 + h] = s;
      } else {
        float sum = s;
#pragma unroll
        for (int off = 1; off < 16; off <<= 1) sum += __shfl_xor(sum, off);
        if (lane == 32) mg[row] = sum * (1.f / 16.f);
      }
    }
  }
}

// ---------------------------------------------------------------------------
// MFMA flash sliding-window attention. Q/KL/VL at PALL cols 2048/3072/4096.
// T14 async-stage split: prefetch next K/V tile into regs BEFORE compute,
// write to LDS after the read-barrier. Q fragments hoisted out of the loop.
// ---------------------------------------------------------------------------
__global__ __launch_bounds__(256) void attn_mfma_kernel(
    const unsigned short* __restrict__ PALL, unsigned short* __restrict__ ACAT) {
  __shared__ unsigned short Qs[64][72];
  __shared__ unsigned short Ks[64][72];
  __shared__ unsigned short Vt[64][72];
  __shared__ unsigned short Ps[64][72];
  int qb = blockIdx.x * 64;
  int bh = blockIdx.y;
  int h = bh & 15, b = bh >> 4;
  int tid = threadIdx.x, lane = tid & 63, wave = tid >> 6;
  int r16 = lane & 15, quad = lane >> 4;
  int m0w = wave * 16;
  const unsigned short* Qg = PALL + (size_t)b * TT * PSA + 2048 + h * 64;
  const unsigned short* Kg = Qg + 1024;
  const unsigned short* Vg = Qg + 2048;
  int sr = tid >> 2, sq = tid & 3;
  int kt0 = qb - (int)WIN;
  if (kt0 < 0) kt0 = 0;

  // stage Q + prefetch first K/V tile into registers
  uint4 kr0, kr1;
  union { uint4 u4[2]; unsigned short s[16]; } vr;
  {
    *(uint4*)&Qs[sr][sq * 16] =
        *(const uint4*)&Qg[(size_t)(qb + sr) * PSA + sq * 16];
    *(uint4*)&Qs[sr][sq * 16 + 8] =
        *(const uint4*)&Qg[(size_t)(qb + sr) * PSA + sq * 16 + 8];
    kr0 = *(const uint4*)&Kg[(size_t)(kt0 + sr) * PSA + sq * 16];
    kr1 = *(const uint4*)&Kg[(size_t)(kt0 + sr) * PSA + sq * 16 + 8];
    vr.u4[0] = *(const uint4*)&Vg[(size_t)(kt0 + sr) * PSA + sq * 16];
    vr.u4[1] = *(const uint4*)&Vg[(size_t)(kt0 + sr) * PSA + sq * 16 + 8];
  }
  __syncthreads();  // Qs visible
  bfrag8 af0 = *(const bfrag8*)&Qs[m0w + r16][quad * 8];
  bfrag8 af1 = *(const bfrag8*)&Qs[m0w + r16][quad * 8 + 32];
  // write first K/V tile to LDS
  {
    *(uint4*)&Ks[sr][sq * 16] = kr0;
    *(uint4*)&Ks[sr][sq * 16 + 8] = kr1;
#pragma unroll
    for (int i = 0; i < 16; ++i) Vt[sq * 16 + i][sr] = vr.s[i];
  }
  __syncthreads();  // Ks/Vt visible

  float m[4], l[4];
  f32x4 o[4];
#pragma unroll
  for (int r = 0; r < 4; ++r) {
    m[r] = -1e30f;
    l[r] = 0.f;
    o[r] = {0.f, 0.f, 0.f, 0.f};
  }

  for (int kt = kt0; kt <= qb; kt += 64) {
    bool more = (kt + 64 <= qb);
    if (more) {  // prefetch next tile; latency hides under compute below
      kr0 = *(const uint4*)&Kg[(size_t)(kt + 64 + sr) * PSA + sq * 16];
      kr1 = *(const uint4*)&Kg[(size_t)(kt + 64 + sr) * PSA + sq * 16 + 8];
      vr.u4[0] = *(const uint4*)&Vg[(size_t)(kt + 64 + sr) * PSA + sq * 16];
      vr.u4[1] = *(const uint4*)&Vg[(size_t)(kt + 64 + sr) * PSA + sq * 16 + 8];
    }
    f32x4 s[4];
#pragma unroll
    for (int j = 0; j < 4; ++j) s[j] = {0.f, 0.f, 0.f, 0.f};
#pragma unroll
    for (int j = 0; j < 4; ++j) {
      bfrag8 b0 = *(const bfrag8*)&Ks[j * 16 + r16][quad * 8];
      bfrag8 b1 = *(const bfrag8*)&Ks[j * 16 + r16][quad * 8 + 32];
      s[j] = __builtin_amdgcn_mfma_f32_16x16x32_bf16(af0, b0, s[j], 0, 0, 0);
      s[j] = __builtin_amdgcn_mfma_f32_16x16x32_bf16(af1, b1, s[j], 0, 0, 0);
    }
    bool oldest = (kt == qb - (int)WIN);
    bool newest = (kt == qb);
#pragma unroll
    for (int r = 0; r < 4; ++r) {
      int il = m0w + quad * 4 + r;
      float sv[4];
#pragma unroll
      for (int j = 0; j < 4; ++j) {
        int jl = j * 16 + r16;
        float v = s[j][r] * 0.125f;
        if (oldest && jl < il) v = -1e30f;
        if (newest && jl > il) v = -1e30f;
        sv[j] = v;
      }
      float mx = fmaxf(fmaxf(sv[0], sv[1]), fmaxf(sv[2], sv[3]));
#pragma unroll
      for (int off = 1; off < 16; off <<= 1) mx = fmaxf(mx, __shfl_xor(mx, off));
      float mn = fmaxf(m[r], mx);
      float al = __expf(m[r] - mn);
      m[r] = mn;
      float rs = 0.f;
#pragma unroll
      for (int j = 0; j < 4; ++j) {
        float p = __expf(sv[j] - mn);
        rs += p;
        Ps[il][j * 16 + r16] = f2bf(p);
      }
#pragma unroll
      for (int off = 1; off < 16; off <<= 1) rs += __shfl_xor(rs, off);
      l[r] = l[r] * al + rs;
#pragma unroll
      for (int j = 0; j < 4; ++j) o[j][r] *= al;
    }
    bfrag8 pa0 = *(const bfrag8*)&Ps[m0w + r16][quad * 8];
    bfrag8 pa1 = *(const bfrag8*)&Ps[m0w + r16][quad * 8 + 32];
#pragma unroll
    for (int j = 0; j < 4; ++j) {
      bfrag8 v0 = *(const bfrag8*)&Vt[j * 16 + r16][quad * 8];
      bfrag8 v1 = *(const bfrag8*)&Vt[j * 16 + r16][quad * 8 + 32];
      o[j] = __builtin_amdgcn_mfma_f32_16x16x32_bf16(pa0, v0, o[j], 0, 0, 0);
      o[j] = __builtin_amdgcn_mfma_f32_16x16x32_bf16(pa1, v1, o[j], 0, 0, 0);
    }
    if (more) {
      __syncthreads();  // all waves done reading Ks/Vt
      *(uint4*)&Ks[sr][sq * 16] = kr0;
      *(uint4*)&Ks[sr][sq * 16 + 8] = kr1;
#pragma unroll
      for (int i = 0; i < 16; ++i) Vt[sq * 16 + i][sr] = vr.s[i];
      __syncthreads();  // next tile visible
    }
  }
#pragma unroll
  for (int r = 0; r < 4; ++r) {
    int row = m0w + quad * 4 + r;
    float inv = 1.f / l[r];
#pragma unroll
    for (int j = 0; j < 4; ++j) {
      ACAT[((size_t)(b * TT + qb + row)) * PSB + 1024 + h * 64 + j * 16 + r16] =
          f2bf(o[j][r] * inv);
    }
  }
}

// ---------------------------------------------------------------------------
// Scan phase A (per (bh,chunk)): M, u_free, Z, P, Q, a. bf16 K/V from PALL.
// ---------------------------------------------------------------------------
__global__ __launch_bounds__(256) void scan_phaseA(
    const unsigned short* __restrict__ PALL, const float* __restrict__ beta,
    const float* __restrict__ g, unsigned short* __restrict__ UFg,
    unsigned short* __restrict__ Zg, unsigned short* __restrict__ Pg,
    unsigned short* __restrict__ Qg, float* __restrict__ Ag) {
  __shared__ unsigned short Kc[64][72];
  __shared__ unsigned short KTb[64][72];
  __shared__ float Vc[64][68];
  __shared__ float Msv[64][68];
  __shared__ unsigned short UFT[64][72];
  __shared__ unsigned short ZTl[64][72];
  __shared__ float aArr[64], iaArr[64], bArr[64], baArr[64], sKT[64];
  __shared__ float aCs;

  int c = blockIdx.x, bh = blockIdx.y;
  int b = bh >> 4, h = bh & 15;
  int tc = c * 64;
  int tid = threadIdx.x, lane = tid & 63, wave = tid >> 6;
  int r16 = lane & 15, quad = lane >> 4;
  int m0w = wave * 16;
  size_t bhc = (size_t)bh * 16 + c;

  const unsigned short* kbase = PALL + ((size_t)b * TT) * PSA + h * 64;
  const unsigned short* vbase = kbase + 1024;
  const float* bbase = beta + ((size_t)b * TT) * HH + h;
  const float* gbase = g + ((size_t)b * TT) * HH + h;

  if (tid < 64) {
    int ts = tc + tid;
    bool pad = (ts > 1022);
    float gv = pad ? 1.f : gbase[(size_t)ts * HH];
    float bv = pad ? 0.f : bbase[(size_t)ts * HH];
    float p = gv;
#pragma unroll
    for (int o = 1; o < 64; o <<= 1) {
      float t = __shfl_up(p, o);
      if (lane >= o) p *= t;
    }
    aArr[tid] = p;
    iaArr[tid] = 1.f / p;
    bArr[tid] = bv;
    baArr[tid] = bv * p;
    float aC = __shfl(p, 63);
    sKT[tid] = aC / p;
    if (tid == 0) aCs = aC;
    Ag[bhc * 64 + tid] = p;
  }
  __syncthreads();
  {
    int r = tid >> 2, q = tid & 3;
    int ts = tc + r;
    float skt = sKT[r];
    union { uint4 u4[2]; unsigned short s[16]; } kv;
    kv.u4[0] = *(const uint4*)&kbase[(size_t)ts * PSA + q * 16];
    kv.u4[1] = *(const uint4*)&kbase[(size_t)ts * PSA + q * 16 + 8];
    *(uint4*)&Kc[r][q * 16] = kv.u4[0];
    *(uint4*)&Kc[r][q * 16 + 8] = kv.u4[1];
#pragma unroll
    for (int i = 0; i < 16; ++i)
      KTb[q * 16 + i][r] = f2bf(bf2f(kv.s[i]) * skt);
    if (ts <= 1022) {
      union { uint4 u4[2]; unsigned short s[16]; } vv;
      vv.u4[0] = *(const uint4*)&vbase[(size_t)(ts + 1) * PSA + q * 16];
      vv.u4[1] = *(const uint4*)&vbase[(size_t)(ts + 1) * PSA + q * 16 + 8];
#pragma unroll
      for (int i = 0; i < 16; ++i) Vc[r][q * 16 + i] = bf2f(vv.s[i]);
    } else {
#pragma unroll
      for (int i = 0; i < 16; ++i) Vc[r][q * 16 + i] = 0.f;
    }
  }
  __syncthreads();
  {
    bfrag8 af0 = *(const bfrag8*)&Kc[m0w + r16][quad * 8];
    bfrag8 af1 = *(const bfrag8*)&Kc[m0w + r16][quad * 8 + 32];
    f32x4 acc1[4];
#pragma unroll
    for (int j = 0; j < 4; ++j) acc1[j] = {0.f, 0.f, 0.f, 0.f};
#pragma unroll
    for (int j = 0; j < 4; ++j) {
      bfrag8 k0 = *(const bfrag8*)&Kc[j * 16 + r16][quad * 8];
      bfrag8 k1 = *(const bfrag8*)&Kc[j * 16 + r16][quad * 8 + 32];
      acc1[j] = __builtin_amdgcn_mfma_f32_16x16x32_bf16(af0, k0, acc1[j], 0, 0, 0);
      acc1[j] = __builtin_amdgcn_mfma_f32_16x16x32_bf16(af1, k1, acc1[j], 0, 0, 0);
    }
#pragma unroll
    for (int j = 0; j < 4; ++j) {
#pragma unroll
      for (int r = 0; r < 4; ++r) {
        int row = m0w + quad * 4 + r;
        int col = j * 16 + r16;
        Msv[row][col] =
            (col < row) ? bArr[row] * aArr[row] * iaArr[col] * acc1[j][r] : 0.f;
      }
    }
  }
  __syncthreads();
  if (wave < 2) {
    float u[64];
    if (wave == 0) {
#pragma unroll
      for (int t = 0; t < 64; ++t) u[t] = bArr[t] * Vc[t][lane];
    } else {
#pragma unroll
      for (int t = 0; t < 64; ++t) u[t] = baArr[t] * bf2f(Kc[t][lane]);
    }
#pragma unroll
    for (int t = 1; t < 64; ++t) {
      float a0 = 0.f, a1 = 0.f, a2 = 0.f, a3 = 0.f;
#pragma unroll
      for (int s4 = 0; s4 * 4 < t; ++s4) {
        float4 mr = *(const float4*)&Msv[t][s4 * 4];
        a0 = fmaf(mr.x, u[s4 * 4 + 0], a0);
        a1 = fmaf(mr.y, u[s4 * 4 + 1], a1);
        a2 = fmaf(mr.z, u[s4 * 4 + 2], a2);
        a3 = fmaf(mr.w, u[s4 * 4 + 3], a3);
      }
      u[t] -= (a0 + a1) + (a2 + a3);
    }
    unsigned short* Tls = (wave == 0) ? &UFT[lane][0] : &ZTl[lane][0];
#pragma unroll
    for (int t2 = 0; t2 < 32; ++t2) {
      unsigned int pk = (unsigned int)f2bf(u[2 * t2]) |
                        ((unsigned int)f2bf(u[2 * t2 + 1]) << 16);
      *(unsigned int*)&Tls[2 * t2] = pk;
    }
    unsigned short* Gn = (wave == 0) ? UFg : Zg;
#pragma unroll
    for (int t = 0; t < 64; ++t) {
      Gn[(bhc * 64 + t) * 64 + lane] = f2bf(u[t]);
    }
  }
  __syncthreads();
  {
    bfrag8 af0 = *(const bfrag8*)&KTb[m0w + r16][quad * 8];
    bfrag8 af1 = *(const bfrag8*)&KTb[m0w + r16][quad * 8 + 32];
    f32x4 accp[4], accq[4];
#pragma unroll
    for (int j = 0; j < 4; ++j) {
      accp[j] = {0.f, 0.f, 0.f, 0.f};
      accq[j] = {0.f, 0.f, 0.f, 0.f};
    }
#pragma unroll
    for (int j = 0; j < 4; ++j) {
      bfrag8 z0 = *(const bfrag8*)&ZTl[j * 16 + r16][quad * 8];
      bfrag8 z1 = *(const bfrag8*)&ZTl[j * 16 + r16][quad * 8 + 32];
      accp[j] = __builtin_amdgcn_mfma_f32_16x16x32_bf16(af0, z0, accp[j], 0, 0, 0);
      accp[j] = __builtin_amdgcn_mfma_f32_16x16x32_bf16(af1, z1, accp[j], 0, 0, 0);
      bfrag8 u0 = *(const bfrag8*)&UFT[j * 16 + r16][quad * 8];
      bfrag8 u1 = *(const bfrag8*)&UFT[j * 16 + r16][quad * 8 + 32];
      accq[j] = __builtin_amdgcn_mfma_f32_16x16x32_bf16(af0, u0, accq[j], 0, 0, 0);
      accq[j] = __builtin_amdgcn_mfma_f32_16x16x32_bf16(af1, u1, accq[j], 0, 0, 0);
    }
    float aC = aCs;
#pragma unroll
    for (int j = 0; j < 4; ++j) {
#pragma unroll
      for (int r = 0; r < 4; ++r) {
        int row = m0w + quad * 4 + r;
        int col = j * 16 + r16;
        float pv = ((row == col) ? aC : 0.f) - accp[j][r];
        Pg[bhc * 4096 + (size_t)row * 64 + col] = f2bf(pv);
        Qg[bhc * 4096 + (size_t)row * 64 + col] = f2bf(accq[j][r]);
      }
    }
  }
}

// ---------------------------------------------------------------------------
// Scan phase B: serial S_{c+1} = P_c S_c + Q_c.
// ---------------------------------------------------------------------------
__global__ __launch_bounds__(256) void scan_phaseB(
    const float* __restrict__ S0, const unsigned short* __restrict__ Pg,
    const unsigned short* __restrict__ Qg, unsigned short* __restrict__ SinTg,
    float* __restrict__ Sf, unsigned short* __restrict__ ACAT) {
  __shared__ unsigned short STb[64][72];
  __shared__ unsigned short Pl[64][72];
  int bh = blockIdx.x;
  int b = bh >> 4, h = bh & 15;
  int tid = threadIdx.x, lane = tid & 63, wave = tid >> 6;
  int r16 = lane & 15, quad = lane >> 4;
  int m0w = wave * 16;
  int rr = tid >> 2, qq = tid & 3;
  {
    const float* s0p = S0 + (size_t)bh * 4096;
#pragma unroll
    for (int i = 0; i < 4; ++i) {
      float4 sv = *(const float4*)&s0p[rr * 64 + qq * 16 + i * 4];
      STb[qq * 16 + i * 4 + 0][rr] = f2bf(sv.x);
      STb[qq * 16 + i * 4 + 1][rr] = f2bf(sv.y);
      STb[qq * 16 + i * 4 + 2][rr] = f2bf(sv.z);
      STb[qq * 16 + i * 4 + 3][rr] = f2bf(sv.w);
    }
    if (tid < 64) ACAT[((size_t)b * TT) * PSB + h * 64 + tid] = 0;
  }
  for (int c = 0; c < 16; ++c) {
    size_t bhc = (size_t)bh * 16 + c;
    __syncthreads();
    {
      uint4 s0v = *(const uint4*)&STb[rr][qq * 16];
      uint4 s1v = *(const uint4*)&STb[rr][qq * 16 + 8];
      *(uint4*)&SinTg[bhc * 4096 + (size_t)rr * 64 + qq * 16] = s0v;
      *(uint4*)&SinTg[bhc * 4096 + (size_t)rr * 64 + qq * 16 + 8] = s1v;
      uint4 p0 = *(const uint4*)&Pg[bhc * 4096 + (size_t)rr * 64 + qq * 16];
      uint4 p1 = *(const uint4*)&Pg[bhc * 4096 + (size_t)rr * 64 + qq * 16 + 8];
      *(uint4*)&Pl[rr][qq * 16] = p0;
      *(uint4*)&Pl[rr][qq * 16 + 8] = p1;
    }
    __syncthreads();
    f32x4 acc[4];
#pragma unroll
    for (int j = 0; j < 4; ++j) acc[j] = {0.f, 0.f, 0.f, 0.f};
    {
      bfrag8 af0 = *(const bfrag8*)&Pl[m0w + r16][quad * 8];
      bfrag8 af1 = *(const bfrag8*)&Pl[m0w + r16][quad * 8 + 32];
#pragma unroll
      for (int j = 0; j < 4; ++j) {
        bfrag8 s0v = *(const bfrag8*)&STb[j * 16 + r16][quad * 8];
        bfrag8 s1v = *(const bfrag8*)&STb[j * 16 + r16][quad * 8 + 32];
        acc[j] = __builtin_amdgcn_mfma_f32_16x16x32_bf16(af0, s0v, acc[j], 0, 0, 0);
        acc[j] = __builtin_amdgcn_mfma_f32_16x16x32_bf16(af1, s1v, acc[j], 0, 0, 0);
      }
    }
    float snew[4][4];
#pragma unroll
    for (int j = 0; j < 4; ++j) {
#pragma unroll
      for (int r = 0; r < 4; ++r) {
        int row = m0w + quad * 4 + r;
        int col = j * 16 + r16;
        snew[j][r] = acc[j][r] + bf2f(Qg[bhc * 4096 + (size_t)row * 64 + col]);
      }
    }
    __syncthreads();
#pragma unroll
    for (int j = 0; j < 4; ++j) {
#pragma unroll
      for (int r = 0; r < 4; ++r) {
        int row = m0w + quad * 4 + r;
        int col = j * 16 + r16;
        STb[col][row] = f2bf(snew[j][r]);
        if (c == 15) Sf[(size_t)bh * 4096 + (size_t)row * 64 + col] = snew[j][r];
      }
    }
  }
}

// ---------------------------------------------------------------------------
// Scan phase C v2: O = diag(a) K S_in + W U -> ACAT col 0.
// LDS 36.5KB (Z/U direct from global); launch_bounds(256,4).
// ---------------------------------------------------------------------------
__global__ __launch_bounds__(256, 4) void scan_phaseC(
    const unsigned short* __restrict__ PALL,
    const unsigned short* __restrict__ UFg,
    const unsigned short* __restrict__ Zg,
    const unsigned short* __restrict__ SinTg, const float* __restrict__ Ag,
    unsigned short* __restrict__ ACAT) {
  __shared__ unsigned short Kc[64][72];
  __shared__ unsigned short SvT[64][72];
  __shared__ unsigned short Wl[64][72];
  __shared__ unsigned short UTl[64][72];
  __shared__ float aA[64], iaA[64];

  int c = blockIdx.x, bh = blockIdx.y;
  int b = bh >> 4, h = bh & 15;
  int tc = c * 64;
  int tid = threadIdx.x, lane = tid & 63, wave = tid >> 6;
  int r16 = lane & 15, quad = lane >> 4;
  int m0w = wave * 16;
  size_t bhc = (size_t)bh * 16 + c;
  const unsigned short* kbase = PALL + ((size_t)b * TT) * PSA + h * 64;

  if (tid < 64) {
    float av = Ag[bhc * 64 + tid];
    aA[tid] = av;
    iaA[tid] = 1.f / av;
  }
  {
    int r = tid >> 2, q = tid & 3;
    int ts = tc + r;
    *(uint4*)&Kc[r][q * 16] = *(const uint4*)&kbase[(size_t)ts * PSA + q * 16];
    *(uint4*)&Kc[r][q * 16 + 8] =
        *(const uint4*)&kbase[(size_t)ts * PSA + q * 16 + 8];
    uint4 sv0 = *(const uint4*)&SinTg[bhc * 4096 + (size_t)r * 64 + q * 16];
    uint4 sv1 = *(const uint4*)&SinTg[bhc * 4096 + (size_t)r * 64 + q * 16 + 8];
    *(uint4*)&SvT[r][q * 16] = sv0;
    *(uint4*)&SvT[r][q * 16 + 8] = sv1;
  }
  // Z fragments direct from global (A-operand layout: row m0w+r16)
  bfrag8 zf0 =
      *(const bfrag8*)&Zg[(bhc * 64 + m0w + r16) * 64 + quad * 8];
  bfrag8 zf1 =
      *(const bfrag8*)&Zg[(bhc * 64 + m0w + r16) * 64 + quad * 8 + 32];
  __syncthreads();
  float op[4][4];
  {
    bfrag8 af0 = *(const bfrag8*)&Kc[m0w + r16][quad * 8];
    bfrag8 af1 = *(const bfrag8*)&Kc[m0w + r16][quad * 8 + 32];
    f32x4 acc1[4], acc2[4], acc3[4];
#pragma unroll
    for (int j = 0; j < 4; ++j) {
      acc1[j] = {0.f, 0.f, 0.f, 0.f};
      acc2[j] = {0.f, 0.f, 0.f, 0.f};
      acc3[j] = {0.f, 0.f, 0.f, 0.f};
    }
#pragma unroll
    for (int j = 0; j < 4; ++j) {
      bfrag8 k0 = *(const bfrag8*)&Kc[j * 16 + r16][quad * 8];
      bfrag8 k1 = *(const bfrag8*)&Kc[j * 16 + r16][quad * 8 + 32];
      acc1[j] = __builtin_amdgcn_mfma_f32_16x16x32_bf16(af0, k0, acc1[j], 0, 0, 0);
      acc1[j] = __builtin_amdgcn_mfma_f32_16x16x32_bf16(af1, k1, acc1[j], 0, 0, 0);
      bfrag8 s0 = *(const bfrag8*)&SvT[j * 16 + r16][quad * 8];
      bfrag8 s1 = *(const bfrag8*)&SvT[j * 16 + r16][quad * 8 + 32];
      acc3[j] = __builtin_amdgcn_mfma_f32_16x16x32_bf16(af0, s0, acc3[j], 0, 0, 0);
      acc3[j] = __builtin_amdgcn_mfma_f32_16x16x32_bf16(af1, s1, acc3[j], 0, 0, 0);
      acc2[j] = __builtin_amdgcn_mfma_f32_16x16x32_bf16(zf0, s0, acc2[j], 0, 0, 0);
      acc2[j] = __builtin_amdgcn_mfma_f32_16x16x32_bf16(zf1, s1, acc2[j], 0, 0, 0);
    }
#pragma unroll
    for (int j = 0; j < 4; ++j) {
#pragma unroll
      for (int r = 0; r < 4; ++r) {
        int row = m0w + quad * 4 + r;
        int col = j * 16 + r16;
        Wl[row][col] = (col <= row) ? f2bf(aA[row] * iaA[col] * acc1[j][r])
                                    : (unsigned short)0;
        // U elementwise direct from global (each thread its own (row,col))
        float uval =
            bf2f(UFg[(bhc * 64 + row) * 64 + col]) - acc2[j][r];
        UTl[col][row] = f2bf(uval);
        op[j][r] = aA[row] * acc3[j][r];
      }
    }
  }
  __syncthreads();
  {
    bfrag8 wf0 = *(const bfrag8*)&Wl[m0w + r16][quad * 8];
    bfrag8 wf1 = *(const bfrag8*)&Wl[m0w + r16][quad * 8 + 32];
    f32x4 acc4[4];
#pragma unroll
    for (int j = 0; j < 4; ++j) acc4[j] = {0.f, 0.f, 0.f, 0.f};
#pragma unroll
    for (int j = 0; j < 4; ++j) {
      bfrag8 u0 = *(const bfrag8*)&UTl[j * 16 + r16][quad * 8];
      bfrag8 u1 = *(const bfrag8*)&UTl[j * 16 + r16][quad * 8 + 32];
      acc4[j] = __builtin_amdgcn_mfma_f32_16x16x32_bf16(wf0, u0, acc4[j], 0, 0, 0);
      acc4[j] = __builtin_amdgcn_mfma_f32_16x16x32_bf16(wf1, u1, acc4[j], 0, 0, 0);
    }
#pragma unroll
    for (int j = 0; j < 4; ++j) {
#pragma unroll
      for (int r = 0; r < 4; ++r) {
        int row = m0w + quad * 4 + r;
        int col = j * 16 + r16;
        int ts = tc + row;
        if (ts < 1023) {
          ACAT[((size_t)b * TT + ts + 1) * PSB + h * 64 + col] =
              f2bf(op[j][r] + acc4[j][r]);
        }
      }
    }
  }
}

// ---------------------------------------------------------------------------
// retrieved = (k_shared @ Sf) * mg -> ACAT col 2048 (bf16). LDS-staged Sf
// (R6 form). Grid (16 t-chunks, 64 bh).
// ---------------------------------------------------------------------------
__global__ __launch_bounds__(256) void retrieve_kernel(
    const unsigned short* __restrict__ PALL, const float* __restrict__ Sf,
    const float* __restrict__ mg, unsigned short* __restrict__ ACAT) {
  __shared__ float Sfs[64][64];  // [k][v]; row-broadcast reads: conflict-free
  int tc = blockIdx.x * 64;
  int bh = blockIdx.y;
  int b = bh >> 4, h = bh & 15;
  int tid = threadIdx.x, lane = tid & 63, wave = tid >> 6;
  const float* sfp = Sf + (size_t)bh * 4096;
#pragma unroll
  for (int i = 0; i < 4; ++i) {
    int e = tid + i * 256;  // float4 index 0..1023
    ((float4*)&Sfs[0][0])[e] = ((const float4*)sfp)[e];
  }
  __syncthreads();
  const unsigned short* kb = PALL + ((size_t)b * TT) * PSA + h * 64;
#pragma unroll 2
  for (int ti = 0; ti < 16; ++ti) {
    int t = tc + wave * 16 + ti;
    size_t bt = (size_t)b * TT + t;
    float kl = bf2f(kb[(size_t)t * PSA + lane]);  // lane = k (coalesced)
    float a0 = 0.f, a1 = 0.f, a2 = 0.f, a3 = 0.f;
#pragma unroll
    for (int k = 0; k < 64; k += 4) {
      a0 = fmaf(__shfl(kl, k + 0), Sfs[k + 0][lane], a0);
      a1 = fmaf(__shfl(kl, k + 1), Sfs[k + 1][lane], a1);
      a2 = fmaf(__shfl(kl, k + 2), Sfs[k + 2][lane], a2);
      a3 = fmaf(__shfl(kl, k + 3), Sfs[k + 3][lane], a3);
    }
    float acc = (a0 + a1) + (a2 + a3);
    ACAT[bt * PSB + 2048 + h * 64 + lane] = f2bf(acc * mg[bt]);
  }
}

// ---------------------------------------------------------------------------
extern "C" void kernel_launch(void* const* d_in, const int* in_sizes, int n_in,
                              void* d_out, int out_size, void* d_ws,
                              size_t ws_size, hipStream_t stream) {
  (void)in_sizes; (void)n_in; (void)out_size; (void)ws_size;
  const float* x       = (const float*)d_in[0];
  const float* S0      = (const float*)d_in[1];
  const float* W_k     = (const float*)d_in[2];
  const float* W_v     = (const float*)d_in[3];
  const float* W_gdn_o = (const float*)d_in[4];
  const float* W_beta  = (const float*)d_in[5];
  const float* b_beta  = (const float*)d_in[6];
  const float* W_g     = (const float*)d_in[7];
  const float* b_g     = (const float*)d_in[8];
  const float* W_lq    = (const float*)d_in[9];
  const float* W_lk    = (const float*)d_in[10];
  const float* W_lv    = (const float*)d_in[11];
  const float* W_swa_o = (const float*)d_in[12];
  const float* W_ret_o = (const float*)d_in[13];
  const float* W_gate  = (const float*)d_in[14];
  const float* b_gate  = (const float*)d_in[15];
  const float* norm_w  = (const float*)d_in[16];
  const int*   ids     = (const int*)d_in[17];
  float* out = (float*)d_out;

  char* ws = (char*)d_ws;
  size_t off = 0;
  auto allocf = [&](size_t n) {
    float* p = (float*)(ws + off);
    off += n * sizeof(float);
    return p;
  };
  auto allocu = [&](size_t n) {
    unsigned short* p = (unsigned short*)(ws + off);
    off += n * sizeof(unsigned short);
    return p;
  };
  const int M = BB * TT;  // 4096
  unsigned short* XNb    = allocu((size_t)M * DD);
  unsigned short* PALL   = allocu((size_t)M * PSA);   // K|V|Q|KL|VL bf16
  unsigned short* ACAT   = allocu((size_t)M * PSB);   // gdn | local | retr
  float*          SPRJ   = allocf((size_t)M * 128);   // gate logits
  unsigned short* WTcat5 = allocu((size_t)NPROJ * 1024);
  unsigned short* WTcat3 = allocu((size_t)1024 * PSB);
  float* BETA = allocf((size_t)M * HH);
  float* Gg   = allocf((size_t)M * HH);
  float* MG   = allocf((size_t)M);
  float* SF   = allocf((size_t)BB * HH * KK * VV);
  const size_t CH = (size_t)BB * HH * 16 * 64 * 64;
  unsigned short* UFg   = allocu(CH);
  unsigned short* Zg    = allocu(CH);
  unsigned short* Pg    = allocu(CH);
  unsigned short* Qg    = allocu(CH);
  unsigned short* SinTg = allocu(CH);
  float* Ag = allocf((size_t)BB * HH * 16 * 64);

  // rmsnorm (4096 blocks) + convert_wt (2304 blocks) fused
  prep_kernel<<<6400, 256, 0, stream>>>(x, norm_w, XNb, W_k, W_v, W_lq, W_lk,
                                        W_lv, W_gdn_o, W_swa_o, W_ret_o,
                                        W_beta, W_g, W_gate, WTcat5, WTcat3);

  gemm_proj_kernel<<<dim3(41, 32), 256, 0, stream>>>(XNb, WTcat5, PALL, SPRJ);

  // knorm (4096 blocks, contiguous per-row) + gates (1024 blocks) fused
  ng_kernel<<<5120, 256, 0, stream>>>(PALL, SPRJ, b_beta, b_g, b_gate, ids,
                                      BETA, Gg, MG);

  scan_phaseA<<<dim3(16, BB * HH), 256, 0, stream>>>(PALL, BETA, Gg, UFg, Zg,
                                                     Pg, Qg, Ag);
  scan_phaseB<<<BB * HH, 256, 0, stream>>>(S0, Pg, Qg, SinTg, SF, ACAT);
  scan_phaseC<<<dim3(16, BB * HH), 256, 0, stream>>>(PALL, UFg, Zg, SinTg, Ag,
                                                     ACAT);

  attn_mfma_kernel<<<dim3(TT / 64, BB * HH), 256, 0, stream>>>(PALL, ACAT);

  retrieve_kernel<<<dim3(TT / 64, BB * HH), 256, 0, stream>>>(PALL, SF, MG,
                                                              ACAT);

  // out = x + [gdn | local*0.3W | retr*mg] @ WTcat3^T  (K=3072, 512 blocks)
  gemm_out_kernel<<<dim3(16, 32), 256, 0, stream>>>(ACAT, WTcat3, out, x, M, DD,
                                                    3072);
}